// Round 3
// baseline (7666.837 us; speedup 1.0000x reference)
//
#include <hip/hip_runtime.h>

#define EPSV  1e-20f
#define BNEPS 1e-5f

// ---------------------------------------------------------------------------
// Weight prep: wn = |w| / (sum_{ci,k}|w| + EPS) per output filter co.
//   wB[ci][tap][co]  = wn[co][ci][ky][kx]        (update conv, [IC][9][OC])
//   wA[co][tap'][ci] = wn[co][ci][2-ky][2-kx]    (ratio conv,  [IC][9][OCA]),
//     OCA = CIN or 4 (padded, for the oc3 ratio kernel).
// ---------------------------------------------------------------------------
template<int CIN, int COUT, int OCA>
__global__ __launch_bounds__(256) void prep_w_kernel(const float* __restrict__ w,
                                                     float* __restrict__ wA,
                                                     float* __restrict__ wB)
{
    const int co  = blockIdx.x;
    const int tid = threadIdx.x;
    const int N   = CIN * 9;
    const float* wrow = w + (size_t)co * N;

    float s = 0.f;
    for (int i = tid; i < N; i += 256) s += fabsf(wrow[i]);
    __shared__ float red[4];
    #pragma unroll
    for (int m = 32; m; m >>= 1) s += __shfl_xor(s, m, 64);
    if ((tid & 63) == 0) red[tid >> 6] = s;
    __syncthreads();
    s = red[0] + red[1] + red[2] + red[3];
    const float rn = 1.f / (s + EPSV);

    for (int i = tid; i < N; i += 256) {
        const int ci = i / 9, tap = i % 9;
        const int ky = tap / 3, kx = tap % 3;
        const float v = fabsf(wrow[i]) * rn;               // wn[co][ci][ky][kx]
        wB[((size_t)ci * 9 + tap) * COUT + co] = v;
        wA[((size_t)co * 9 + (2 - ky) * 3 + (2 - kx)) * OCA + ci] = v;
    }
}

// ---------------------------------------------------------------------------
// Input prep: xn = relu(x) / (sum_c relu(x) + EPS), per pixel.
// ---------------------------------------------------------------------------
template<int C>
__global__ __launch_bounds__(256) void xn_kernel(const float* __restrict__ in,
                                                 float* __restrict__ xn,
                                                 int npx, int HW)
{
    const int p = blockIdx.x * 256 + threadIdx.x;
    if (p >= npx) return;
    const int b = p / HW, r = p % HW;
    const float* ip = in + (size_t)b * C * HW + r;
    float*       op = xn + (size_t)b * C * HW + r;
    float s = 0.f;
    #pragma unroll 4
    for (int c = 0; c < C; ++c) s += fmaxf(ip[(size_t)c * HW], 0.f);
    const float rs = 1.f / (s + EPSV);
    #pragma unroll 4
    for (int c = 0; c < C; ++c) op[(size_t)c * HW] = fmaxf(ip[(size_t)c * HW], 0.f) * rs;
}

// h_u = 1 everywhere; S = sum over channels = COUT.
__global__ __launch_bounds__(256) void init_h_kernel(float* __restrict__ h, float* __restrict__ S,
                                                     int nh, int ns, float cval)
{
    const int i = blockIdx.x * 256 + threadIdx.x;
    if (i < nh) h[i] = 1.f;
    if (i < ns) S[i] = cval;
}

// ---------------------------------------------------------------------------
// Specialized block-0 ratio conv: IC inputs -> 3 outputs (padded weight rows).
// 256 threads own 512 px (32x16 tile, 2 px each); each thread accumulates all
// 3 output channels. Weights [IC][9][4] staged ONCE in LDS (uniform broadcast
// reads). Input chunks (ICB channels) register-prefetched (T14 split).
//   ratio = xn / (conv(h/S, wA) + EPS)
// ---------------------------------------------------------------------------
template<int IC, int ICB, int TH, int TW>
__global__ __launch_bounds__(256) void ratio_oc3_kernel(
    const float* __restrict__ h, const float* __restrict__ wA4,
    const float* __restrict__ xn, float* __restrict__ ratio,
    const float* __restrict__ S, int H, int W)
{
    constexpr int NPX = 2;
    constexpr int HS = TH + 2, WSg = TW + 2;
    constexpr int WS = ((WSg + 3) / 4) * 4;
    constexpr int SPR = TW / NPX;            // 8 (pow2)
    constexpr int NCH = IC / ICB;
    constexpr int NIF = ICB * HS * WSg;
    constexpr int IREG = (NIF + 255) / 256;
    static_assert(TH * TW == 256 * NPX, "tile size");

    __shared__ float w_l[IC * 36];
    __shared__ float in_t[ICB * HS * WS];
    __shared__ float rS[HS * WSg];

    const int tid  = threadIdx.x;
    const int row  = tid / SPR;
    const int col0 = (tid & (SPR - 1)) * NPX;
    const int x0 = blockIdx.x * TW, y0 = blockIdx.y * TH;
    const int b  = blockIdx.z;
    const int HW = H * W;

    // weights: one-time full stage (IC*9 float4)
    {
        const float4* wsrc = reinterpret_cast<const float4*>(wA4);
        float4* wdst = reinterpret_cast<float4*>(w_l);
        #pragma unroll
        for (int r = 0; r < (IC * 9 + 255) / 256; ++r) {
            const int i = tid + r * 256;
            if (i < IC * 9) wdst[i] = wsrc[i];
        }
    }
    // rS tile
    for (int i = tid; i < HS * WSg; i += 256) {
        const int yy = y0 + i / WSg - 1, xx = x0 + i % WSg - 1;
        float sv = 0.f;
        if (yy >= 0 && yy < H && xx >= 0 && xx < W)
            sv = S[(size_t)b * HW + (size_t)yy * W + xx];
        rS[i] = 1.f / (sv + EPSV);
    }

    float pre[IREG];
    // prologue: load chunk 0
    #pragma unroll
    for (int r = 0; r < IREG; ++r) {
        const int i = tid + r * 256;
        float v = 0.f;
        if (i < NIF) {
            const int ic = i / (HS * WSg), rr = (i % (HS * WSg)) / WSg, cc = i % WSg;
            const int yy = y0 + rr - 1, xx = x0 + cc - 1;
            if (yy >= 0 && yy < H && xx >= 0 && xx < W)
                v = h[((size_t)(b * IC + ic)) * HW + (size_t)yy * W + xx];
        }
        pre[r] = v;
    }
    __syncthreads();      // w_l, rS ready
    #pragma unroll
    for (int r = 0; r < IREG; ++r) {
        const int i = tid + r * 256;
        if (i < NIF) {
            const int ic = i / (HS * WSg), rr = (i % (HS * WSg)) / WSg, cc = i % WSg;
            in_t[ic * (HS * WS) + rr * WS + cc] = pre[r] * rS[rr * WSg + cc];
        }
    }
    __syncthreads();

    float acc0[NPX], acc1[NPX], acc2[NPX];
    #pragma unroll
    for (int p = 0; p < NPX; ++p) { acc0[p] = 0.f; acc1[p] = 0.f; acc2[p] = 0.f; }

    for (int c = 0; c < NCH; ++c) {
        // prefetch next chunk into regs (overlaps with compute below)
        if (c + 1 < NCH) {
            #pragma unroll
            for (int r = 0; r < IREG; ++r) {
                const int i = tid + r * 256;
                float v = 0.f;
                if (i < NIF) {
                    const int ic = i / (HS * WSg), rr = (i % (HS * WSg)) / WSg, cc = i % WSg;
                    const int yy = y0 + rr - 1, xx = x0 + cc - 1;
                    if (yy >= 0 && yy < H && xx >= 0 && xx < W)
                        v = h[((size_t)(b * IC + (c + 1) * ICB + ic)) * HW + (size_t)yy * W + xx];
                }
                pre[r] = v;
            }
        }
        // compute current chunk
        for (int ic = 0; ic < ICB; ++ic) {
            const float* ib = in_t + ic * (HS * WS) + row * WS + col0;
            float win[3][4];
            #pragma unroll
            for (int dy = 0; dy < 3; ++dy) {
                const float2 a = *reinterpret_cast<const float2*>(ib + dy * WS);
                const float2 bb = *reinterpret_cast<const float2*>(ib + dy * WS + 2);
                win[dy][0] = a.x; win[dy][1] = a.y; win[dy][2] = bb.x; win[dy][3] = bb.y;
            }
            const float* wb = w_l + (c * ICB + ic) * 36;
            #pragma unroll
            for (int t = 0; t < 9; ++t) {
                const float4 wv = *reinterpret_cast<const float4*>(wb + t * 4);
                const int ky = t / 3, kx = t % 3;
                #pragma unroll
                for (int p = 0; p < NPX; ++p) {
                    const float v = win[ky][kx + p];
                    acc0[p] = fmaf(v, wv.x, acc0[p]);
                    acc1[p] = fmaf(v, wv.y, acc1[p]);
                    acc2[p] = fmaf(v, wv.z, acc2[p]);
                }
            }
        }
        __syncthreads();
        if (c + 1 < NCH) {
            #pragma unroll
            for (int r = 0; r < IREG; ++r) {
                const int i = tid + r * 256;
                if (i < NIF) {
                    const int ic = i / (HS * WSg), rr = (i % (HS * WSg)) / WSg, cc = i % WSg;
                    in_t[ic * (HS * WS) + rr * WS + cc] = pre[r] * rS[rr * WSg + cc];
                }
            }
        }
        __syncthreads();
    }

    const int gy = y0 + row, gx0 = x0 + col0;
    const size_t p0 = ((size_t)(b * 3)) * HW + (size_t)gy * W + gx0;
    float* accs[3] = {acc0, acc1, acc2};
    #pragma unroll
    for (int oc = 0; oc < 3; ++oc) {
        const size_t idx = p0 + (size_t)oc * HW;
        const float2 av = *reinterpret_cast<const float2*>(xn + idx);
        float2 ov;
        ov.x = av.x / (accs[oc][0] + EPSV);
        ov.y = av.y / (accs[oc][1] + EPSV);
        *reinterpret_cast<float2*>(ratio + idx) = ov;
    }
}

// ---------------------------------------------------------------------------
// 3x3 'same' conv v3: register-tiled with T14 reg-prefetch double buffering.
//   Workgroup = 256 threads = PXT pixel-slots x OCG oc-groups; thread computes
//   NPX=4 contiguous pixels x NOC output channels. Input+weight chunks are
//   prefetched to registers while the previous chunk computes.
// ---------------------------------------------------------------------------
template<int IC, int OC, int TH, int TW, int PXT, int NPX, int NOC, int ICB,
         bool NORM_IN, bool UPDATE>
__global__ __launch_bounds__(256) void conv3v3_kernel(
    const float* __restrict__ in,    // [B,IC,H,W]
    const float* __restrict__ wgt,   // [IC][9][OC]
    const float* __restrict__ aux,   // ratio mode: xn [B,OC,H,W]
    float* __restrict__ out,         // ratio: [B,OC,H,W]; update: h inout
    const float* __restrict__ Sin,   // NORM_IN: per-pixel channel sums of `in`
    float* __restrict__ Sout,        // UPDATE: per-pixel channel sums of new h
    int H, int W)
{
    constexpr int OCG = 256 / PXT;
    constexpr int TPX = TH * TW;
    constexpr int SPR = TW / NPX;
    constexpr int HS  = TH + 2;
    constexpr int WSg = TW + 2;
    constexpr int WS  = ((WSg + 3) / 4) * 4;
    constexpr int NCH = IC / ICB;
    constexpr int NIF = ICB * HS * WSg;
    constexpr int IREG = (NIF + 255) / 256;
    constexpr int NWF = ICB * 9 * OC;
    constexpr int NW4 = NWF / 4;
    constexpr int WREG = (NW4 + 255) / 256;
    static_assert(TPX == PXT * NPX, "tile mismatch");
    static_assert(OCG * NOC >= OC, "oc coverage");
    static_assert(NPX == 4, "NPX");
    static_assert(NOC % 4 == 0, "NOC%4");
    static_assert(NWF % 4 == 0, "w f4");
    static_assert(IC % ICB == 0, "chunks");

    __shared__ float in_t[ICB * HS * WS];
    __shared__ float w_t[NWF];
    __shared__ float rS[NORM_IN ? HS * WSg : 1];
    __shared__ float red[UPDATE ? OCG * TPX : 1];

    const int tid  = threadIdx.x;
    const int pxs  = tid % PXT;
    const int ocg  = tid / PXT;
    const int row  = pxs / SPR;
    const int col0 = (pxs % SPR) * NPX;
    const int x0 = blockIdx.x * TW, y0 = blockIdx.y * TH;
    const int b  = blockIdx.z;
    const int HW = H * W;

    if constexpr (NORM_IN) {
        for (int i = tid; i < HS * WSg; i += 256) {
            const int yy = y0 + i / WSg - 1, xx = x0 + i % WSg - 1;
            float sv = 0.f;
            if (yy >= 0 && yy < H && xx >= 0 && xx < W)
                sv = Sin[(size_t)b * HW + (size_t)yy * W + xx];
            rS[i] = 1.f / (sv + EPSV);
        }
    }

    float ipre[IREG];
    float4 wpre[WREG];
    const float4* wsrc4 = reinterpret_cast<const float4*>(wgt);

    // prologue: load chunk 0 into regs
    #pragma unroll
    for (int r = 0; r < IREG; ++r) {
        const int i = tid + r * 256;
        float v = 0.f;
        if (i < NIF) {
            const int ic = i / (HS * WSg), rr = (i % (HS * WSg)) / WSg, cc = i % WSg;
            const int yy = y0 + rr - 1, xx = x0 + cc - 1;
            if (yy >= 0 && yy < H && xx >= 0 && xx < W)
                v = in[((size_t)(b * IC + ic)) * HW + (size_t)yy * W + xx];
        }
        ipre[r] = v;
    }
    #pragma unroll
    for (int r = 0; r < WREG; ++r) {
        const int i = tid + r * 256;
        if (i < NW4) wpre[r] = wsrc4[i];
    }
    __syncthreads();    // rS ready
    #pragma unroll
    for (int r = 0; r < IREG; ++r) {
        const int i = tid + r * 256;
        if (i < NIF) {
            const int ic = i / (HS * WSg), rr = (i % (HS * WSg)) / WSg, cc = i % WSg;
            float v = ipre[r];
            if constexpr (NORM_IN) v *= rS[rr * WSg + cc];
            in_t[ic * (HS * WS) + rr * WS + cc] = v;
        }
    }
    {
        float4* wdst = reinterpret_cast<float4*>(w_t);
        #pragma unroll
        for (int r = 0; r < WREG; ++r) {
            const int i = tid + r * 256;
            if (i < NW4) wdst[i] = wpre[r];
        }
    }
    __syncthreads();

    float acc[NOC][NPX];
    #pragma unroll
    for (int j = 0; j < NOC; ++j)
        #pragma unroll
        for (int p = 0; p < NPX; ++p) acc[j][p] = 0.f;

    for (int c = 0; c < NCH; ++c) {
        // prefetch next chunk
        if (c + 1 < NCH) {
            #pragma unroll
            for (int r = 0; r < IREG; ++r) {
                const int i = tid + r * 256;
                float v = 0.f;
                if (i < NIF) {
                    const int ic = i / (HS * WSg), rr = (i % (HS * WSg)) / WSg, cc = i % WSg;
                    const int yy = y0 + rr - 1, xx = x0 + cc - 1;
                    if (yy >= 0 && yy < H && xx >= 0 && xx < W)
                        v = in[((size_t)(b * IC + (c + 1) * ICB + ic)) * HW + (size_t)yy * W + xx];
                }
                ipre[r] = v;
            }
            #pragma unroll
            for (int r = 0; r < WREG; ++r) {
                const int i = tid + r * 256;
                if (i < NW4) wpre[r] = wsrc4[(size_t)(c + 1) * NW4 + i];
            }
        }
        // compute current chunk
        for (int ic = 0; ic < ICB; ++ic) {
            const float* wbase = w_t + ic * 9 * OC;
            const float* ibase = in_t + ic * (HS * WS) + row * WS + col0;

            float win[3][6];
            #pragma unroll
            for (int dy = 0; dy < 3; ++dy) {
                const float* rp = ibase + dy * WS;
                const float4 a = *reinterpret_cast<const float4*>(rp);
                const float2 cxy = *reinterpret_cast<const float2*>(rp + 4);
                win[dy][0] = a.x; win[dy][1] = a.y; win[dy][2] = a.z; win[dy][3] = a.w;
                win[dy][4] = cxy.x; win[dy][5] = cxy.y;
            }
            #pragma unroll
            for (int t = 0; t < 9; ++t) {
                const int ky = t / 3, kx = t % 3;
                #pragma unroll
                for (int j4 = 0; j4 < NOC / 4; ++j4) {
                    const float4 wv = *reinterpret_cast<const float4*>(
                        wbase + t * OC + ocg * NOC + j4 * 4);
                    #pragma unroll
                    for (int p = 0; p < NPX; ++p) {
                        const float v = win[ky][kx + p];
                        acc[j4 * 4 + 0][p] = fmaf(v, wv.x, acc[j4 * 4 + 0][p]);
                        acc[j4 * 4 + 1][p] = fmaf(v, wv.y, acc[j4 * 4 + 1][p]);
                        acc[j4 * 4 + 2][p] = fmaf(v, wv.z, acc[j4 * 4 + 2][p]);
                        acc[j4 * 4 + 3][p] = fmaf(v, wv.w, acc[j4 * 4 + 3][p]);
                    }
                }
            }
        }
        __syncthreads();
        if (c + 1 < NCH) {
            #pragma unroll
            for (int r = 0; r < IREG; ++r) {
                const int i = tid + r * 256;
                if (i < NIF) {
                    const int ic = i / (HS * WSg), rr = (i % (HS * WSg)) / WSg, cc = i % WSg;
                    float v = ipre[r];
                    if constexpr (NORM_IN) v *= rS[rr * WSg + cc];
                    in_t[ic * (HS * WS) + rr * WS + cc] = v;
                }
            }
            float4* wdst = reinterpret_cast<float4*>(w_t);
            #pragma unroll
            for (int r = 0; r < WREG; ++r) {
                const int i = tid + r * 256;
                if (i < NW4) wdst[i] = wpre[r];
            }
            __syncthreads();
        }
    }

    const int gy = y0 + row, gx0 = x0 + col0;

    if constexpr (!UPDATE) {
        #pragma unroll
        for (int j = 0; j < NOC; ++j) {
            const int oc = ocg * NOC + j;
            if constexpr (OCG * NOC > OC) { if (oc >= OC) continue; }
            const size_t idx = ((size_t)(b * OC + oc)) * HW + (size_t)gy * W + gx0;
            const float4 av = *reinterpret_cast<const float4*>(aux + idx);
            float4 ov;
            ov.x = av.x / (acc[j][0] + EPSV);
            ov.y = av.y / (acc[j][1] + EPSV);
            ov.z = av.z / (acc[j][2] + EPSV);
            ov.w = av.w / (acc[j][3] + EPSV);
            *reinterpret_cast<float4*>(out + idx) = ov;
        }
    } else {
        float psum[NPX];
        #pragma unroll
        for (int p = 0; p < NPX; ++p) psum[p] = 0.f;
        #pragma unroll
        for (int j = 0; j < NOC; ++j) {
            const int oc = ocg * NOC + j;
            if constexpr (OCG * NOC > OC) { if (oc >= OC) continue; }
            const size_t idx = ((size_t)(b * OC + oc)) * HW + (size_t)gy * W + gx0;
            float4 hv = *reinterpret_cast<const float4*>(out + idx);
            hv.x *= acc[j][0]; hv.y *= acc[j][1]; hv.z *= acc[j][2]; hv.w *= acc[j][3];
            psum[0] += hv.x; psum[1] += hv.y; psum[2] += hv.z; psum[3] += hv.w;
            *reinterpret_cast<float4*>(out + idx) = hv;
        }
        const int pix0 = row * TW + col0;
        #pragma unroll
        for (int p = 0; p < NPX; ++p) red[ocg * TPX + pix0 + p] = psum[p];
        __syncthreads();
        if (tid < TPX) {
            float s = 0.f;
            #pragma unroll
            for (int g = 0; g < OCG; ++g) s += red[g * TPX + tid];
            const int py = tid / TW, pxx = tid % TW;
            Sout[(size_t)b * HW + (size_t)(y0 + py) * W + (x0 + pxx)] = s;
        }
    }
}

// ---------------------------------------------------------------------------
// Post pass 1: y = relu(W1 . (h/S) + bias); per-workgroup partial (sum y, sum y^2)
// ---------------------------------------------------------------------------
template<int C>
__global__ __launch_bounds__(256) void post1_kernel(
    const float* __restrict__ h, const float* __restrict__ S,
    const float* __restrict__ w1, const float* __restrict__ bias,
    float* __restrict__ part, int H, int W)
{
    constexpr int NOC = C / 8;
    __shared__ float h_t[C * 32];
    __shared__ float sS[32];
    const int tid = threadIdx.x;
    const int px = tid & 31, ocg = tid >> 5;
    const int x0 = blockIdx.x * 8, y0 = blockIdx.y * 4, b = blockIdx.z;
    const int HW = H * W;

    if (tid < 32) {
        const int gy = y0 + (tid >> 3), gx = x0 + (tid & 7);
        sS[tid] = 1.f / (S[(size_t)b * HW + gy * W + gx] + EPSV);
    }
    __syncthreads();
    for (int i = tid; i < C * 32; i += 256) {
        const int c = i >> 5, p = i & 31;
        const int gy = y0 + (p >> 3), gx = x0 + (p & 7);
        h_t[i] = h[((size_t)(b * C + c)) * HW + gy * W + gx] * sS[p];
    }
    __syncthreads();

    const int wgid = (b * gridDim.y + blockIdx.y) * gridDim.x + blockIdx.x;
    for (int j = 0; j < NOC; ++j) {
        const int oc = ocg * NOC + j;
        const float* wrow = w1 + (size_t)oc * C;
        float a = 0.f;
        #pragma unroll 4
        for (int co = 0; co < C; ++co) a = fmaf(wrow[co], h_t[co * 32 + px], a);
        float y  = fmaxf(a + bias[oc], 0.f);
        float y2 = y * y;
        #pragma unroll
        for (int m = 16; m; m >>= 1) { y += __shfl_xor(y, m, 32); y2 += __shfl_xor(y2, m, 32); }
        if (px == 0) {
            part[((size_t)wgid * C + oc) * 2 + 0] = y;
            part[((size_t)wgid * C + oc) * 2 + 1] = y2;
        }
    }
}

// Reduce partials -> per-channel (scale, shift) for BN affine.
template<int C>
__global__ __launch_bounds__(256) void stats_kernel(const float* __restrict__ part, int nwg, float invM,
                                                    const float* __restrict__ gamma,
                                                    const float* __restrict__ beta,
                                                    float* __restrict__ stats)
{
    const int oc = blockIdx.x;
    const int tid = threadIdx.x;
    float s1 = 0.f, s2 = 0.f;
    for (int w = tid; w < nwg; w += 256) {
        s1 += part[((size_t)w * C + oc) * 2 + 0];
        s2 += part[((size_t)w * C + oc) * 2 + 1];
    }
    __shared__ float r1[4], r2[4];
    #pragma unroll
    for (int m = 32; m; m >>= 1) { s1 += __shfl_xor(s1, m, 64); s2 += __shfl_xor(s2, m, 64); }
    if ((tid & 63) == 0) { r1[tid >> 6] = s1; r2[tid >> 6] = s2; }
    __syncthreads();
    if (tid == 0) {
        s1 = r1[0] + r1[1] + r1[2] + r1[3];
        s2 = r2[0] + r2[1] + r2[2] + r2[3];
        const float mean = s1 * invM;
        const float var  = s2 * invM - mean * mean;
        const float rstd = rsqrtf(var + BNEPS);
        const float scale = gamma[oc] * rstd;
        stats[oc]     = scale;
        stats[C + oc] = beta[oc] - mean * scale;
    }
}

// Post pass 2: recompute y, apply BN affine, 2x2 avgpool, write block output.
template<int C>
__global__ __launch_bounds__(256) void post2_kernel(
    const float* __restrict__ h, const float* __restrict__ S,
    const float* __restrict__ w1, const float* __restrict__ bias,
    const float* __restrict__ stats, float* __restrict__ out, int H, int W)
{
    constexpr int NOC = C / 8;
    __shared__ float h_t[C * 32];
    __shared__ float sS[32];
    __shared__ float y_t[8 * 32];
    const int tid = threadIdx.x;
    const int px = tid & 31, ocg = tid >> 5;
    const int x0 = blockIdx.x * 8, y0 = blockIdx.y * 4, b = blockIdx.z;
    const int HW = H * W;

    if (tid < 32) {
        const int gy = y0 + (tid >> 3), gx = x0 + (tid & 7);
        sS[tid] = 1.f / (S[(size_t)b * HW + gy * W + gx] + EPSV);
    }
    __syncthreads();
    for (int i = tid; i < C * 32; i += 256) {
        const int c = i >> 5, p = i & 31;
        const int gy = y0 + (p >> 3), gx = x0 + (p & 7);
        h_t[i] = h[((size_t)(b * C + c)) * HW + gy * W + gx] * sS[p];
    }
    __syncthreads();

    const int Ho = H >> 1, Wo = W >> 1;
    for (int j = 0; j < NOC; ++j) {
        const int oc = ocg * NOC + j;
        const float* wrow = w1 + (size_t)oc * C;
        float a = 0.f;
        #pragma unroll 4
        for (int co = 0; co < C; ++co) a = fmaf(wrow[co], h_t[co * 32 + px], a);
        float y = fmaxf(a + bias[oc], 0.f);
        y = y * stats[oc] + stats[C + oc];
        y_t[ocg * 32 + px] = y;
        __syncthreads();
        if (tid < 64) {
            const int o8 = tid >> 3, pp = tid & 7;
            const int ppy = pp >> 2, ppx = pp & 3;
            const float* yr = y_t + o8 * 32 + ppy * 16 + ppx * 2;
            const float v = (yr[0] + yr[1] + yr[8] + yr[9]) * 0.25f;
            const int oco = o8 * NOC + j;
            out[((size_t)(b * C + oco)) * Ho * Wo + ((blockIdx.y << 1) + ppy) * Wo
                + (blockIdx.x << 2) + ppx] = v;
        }
        __syncthreads();
    }
}

// ---------------------------------------------------------------------------
// Drivers
// ---------------------------------------------------------------------------
static void post_phase(const float* h, const float* S, const float* w1, const float* bias,
                       const float* gamma, const float* beta, float* pout,
                       float* part, float* stats, int C, int H, int W, hipStream_t stream)
{
    const int B = 16, HW = H * W;
    dim3 pg(W / 8, H / 4, B);
    const int nwg = pg.x * pg.y * pg.z;
    if (C == 64) {
        post1_kernel<64><<<pg, 256, 0, stream>>>(h, S, w1, bias, part, H, W);
        stats_kernel<64><<<64, 256, 0, stream>>>(part, nwg, 1.0f / (float)(B * HW), gamma, beta, stats);
        post2_kernel<64><<<pg, 256, 0, stream>>>(h, S, w1, bias, stats, pout, H, W);
    } else if (C == 128) {
        post1_kernel<128><<<pg, 256, 0, stream>>>(h, S, w1, bias, part, H, W);
        stats_kernel<128><<<128, 256, 0, stream>>>(part, nwg, 1.0f / (float)(B * HW), gamma, beta, stats);
        post2_kernel<128><<<pg, 256, 0, stream>>>(h, S, w1, bias, stats, pout, H, W);
    } else {
        post1_kernel<256><<<pg, 256, 0, stream>>>(h, S, w1, bias, part, H, W);
        stats_kernel<256><<<256, 256, 0, stream>>>(part, nwg, 1.0f / (float)(B * HW), gamma, beta, stats);
        post2_kernel<256><<<pg, 256, 0, stream>>>(h, S, w1, bias, stats, pout, H, W);
    }
}

extern "C" void kernel_launch(void* const* d_in, const int* in_sizes, int n_in,
                              void* d_out, int out_size, void* d_ws, size_t ws_size,
                              hipStream_t stream)
{
    const float* x = (const float*)d_in[0];
    float* ws    = (float*)d_ws;
    float* h     = ws;                    // 16,777,216
    float* xn    = h     + 16777216;      //  4,194,304
    float* ratio = xn    + 4194304;       //  4,194,304
    float* out0  = ratio + 4194304;       //  4,194,304
    float* out1  = out0  + 4194304;       //  2,097,152
    float* S     = out1  + 2097152;       //    262,144
    float* wA    = S     + 262144;        //    294,912
    float* wB    = wA    + 294912;        //    294,912
    float* part  = wB    + 294912;        //  1,048,576
    float* stats = part  + 1048576;       //        512

    const int B = 16;

    // ---------------- Block 0: Cin=3, Cout=64, 128x128 ----------------
    {
        const int H = 128, W = 128, HW = H * W;
        prep_w_kernel<3, 64, 4><<<64, 256, 0, stream>>>((const float*)d_in[1], wA, wB);
        const int npx = B * HW;
        xn_kernel<3><<<(npx + 255) / 256, 256, 0, stream>>>(x, xn, npx, HW);
        const int nh = B * 64 * HW;
        init_h_kernel<<<(nh + 255) / 256, 256, 0, stream>>>(h, S, nh, npx, 64.f);
        for (int it = 0; it < 5; ++it) {
            ratio_oc3_kernel<64, 8, 32, 16>
                <<<dim3(W / 16, H / 32, B), 256, 0, stream>>>(h, wA, xn, ratio, S, H, W);
            conv3v3_kernel<3, 64, 16, 16, 64, 4, 16, 3, false, true>
                <<<dim3(W / 16, H / 16, B), 256, 0, stream>>>(ratio, wB, nullptr, h, nullptr, S, H, W);
        }
        post_phase(h, S, (const float*)d_in[2], (const float*)d_in[3],
                   (const float*)d_in[4], (const float*)d_in[5], out0, part, stats, 64, H, W, stream);
    }

    // ---------------- Block 1: Cin=64, Cout=128, 64x64 ----------------
    {
        const int H = 64, W = 64, HW = H * W;
        prep_w_kernel<64, 128, 64><<<128, 256, 0, stream>>>((const float*)d_in[6], wA, wB);
        const int npx = B * HW;
        xn_kernel<64><<<(npx + 255) / 256, 256, 0, stream>>>(out0, xn, npx, HW);
        const int nh = B * 128 * HW;
        init_h_kernel<<<(nh + 255) / 256, 256, 0, stream>>>(h, S, nh, npx, 128.f);
        for (int it = 0; it < 5; ++it) {
            conv3v3_kernel<128, 64, 16, 8, 32, 4, 8, 8, true, false>
                <<<dim3(W / 8, H / 16, B), 256, 0, stream>>>(h, wA, xn, ratio, S, nullptr, H, W);
            conv3v3_kernel<64, 128, 16, 8, 32, 4, 16, 8, false, true>
                <<<dim3(W / 8, H / 16, B), 256, 0, stream>>>(ratio, wB, nullptr, h, nullptr, S, H, W);
        }
        post_phase(h, S, (const float*)d_in[7], (const float*)d_in[8],
                   (const float*)d_in[9], (const float*)d_in[10], out1, part, stats, 128, H, W, stream);
    }

    // ---------------- Block 2: Cin=128, Cout=256, 32x32 ----------------
    {
        const int H = 32, W = 32, HW = H * W;
        prep_w_kernel<128, 256, 128><<<256, 256, 0, stream>>>((const float*)d_in[11], wA, wB);
        const int npx = B * HW;
        xn_kernel<128><<<(npx + 255) / 256, 256, 0, stream>>>(out1, xn, npx, HW);
        const int nh = B * 256 * HW;
        init_h_kernel<<<(nh + 255) / 256, 256, 0, stream>>>(h, S, nh, npx, 256.f);
        for (int it = 0; it < 5; ++it) {
            conv3v3_kernel<256, 128, 4, 8, 8, 4, 4, 8, true, false>
                <<<dim3(W / 8, H / 4, B), 256, 0, stream>>>(h, wA, xn, ratio, S, nullptr, H, W);
            conv3v3_kernel<128, 256, 4, 8, 8, 4, 8, 4, false, true>
                <<<dim3(W / 8, H / 4, B), 256, 0, stream>>>(ratio, wB, nullptr, h, nullptr, S, H, W);
        }
        post_phase(h, S, (const float*)d_in[12], (const float*)d_in[13],
                   (const float*)d_in[14], (const float*)d_in[15], (float*)d_out, part, stats, 256, H, W, stream);
    }
}

// Round 4
// 3520.265 us; speedup vs baseline: 2.1779x; 2.1779x over previous
//
#include <hip/hip_runtime.h>

#define EPSV  1e-20f
#define BNEPS 1e-5f

typedef _Float16 f16x8 __attribute__((ext_vector_type(8)));
typedef float    f32x4 __attribute__((ext_vector_type(4)));

__device__ inline unsigned pack2f16(float a, float b) {
    unsigned short ua = __builtin_bit_cast(unsigned short, (_Float16)a);
    unsigned short ub = __builtin_bit_cast(unsigned short, (_Float16)b);
    return ((unsigned)ub << 16) | ua;
}

// ---------------------------------------------------------------------------
// Weight prep (block0, fp32): wn = |w| / (sum + EPS).
//   wB[ci][tap][co]  (update conv [IC][9][OC]) ; wA[co][tap'][ci] padded OCA.
// ---------------------------------------------------------------------------
template<int CIN, int COUT, int OCA>
__global__ __launch_bounds__(256) void prep_w_kernel(const float* __restrict__ w,
                                                     float* __restrict__ wA,
                                                     float* __restrict__ wB)
{
    const int co  = blockIdx.x;
    const int tid = threadIdx.x;
    const int N   = CIN * 9;
    const float* wrow = w + (size_t)co * N;

    float s = 0.f;
    for (int i = tid; i < N; i += 256) s += fabsf(wrow[i]);
    __shared__ float red[4];
    #pragma unroll
    for (int m = 32; m; m >>= 1) s += __shfl_xor(s, m, 64);
    if ((tid & 63) == 0) red[tid >> 6] = s;
    __syncthreads();
    s = red[0] + red[1] + red[2] + red[3];
    const float rn = 1.f / (s + EPSV);

    for (int i = tid; i < N; i += 256) {
        const int ci = i / 9, tap = i % 9;
        const int ky = tap / 3, kx = tap % 3;
        const float v = fabsf(wrow[i]) * rn;
        wB[((size_t)ci * 9 + tap) * COUT + co] = v;
        wA[((size_t)co * 9 + (2 - ky) * 3 + (2 - kx)) * OCA + ci] = v;
    }
}

// ---------------------------------------------------------------------------
// Weight prep (blocks 1/2, f16 GEMM layouts):
//   wBh[tap][co][ci]   (update conv: n=co over COUT, k=ci over CIN)
//   wAh[tap'][ci][co]  (ratio  conv: n=ci over CIN,  k=co over COUT)
// ---------------------------------------------------------------------------
template<int CIN, int COUT>
__global__ __launch_bounds__(256) void prep_w_f16_kernel(const float* __restrict__ w,
                                                         _Float16* __restrict__ wAh,
                                                         _Float16* __restrict__ wBh)
{
    const int co  = blockIdx.x;
    const int tid = threadIdx.x;
    const int N   = CIN * 9;
    const float* wrow = w + (size_t)co * N;

    float s = 0.f;
    for (int i = tid; i < N; i += 256) s += fabsf(wrow[i]);
    __shared__ float red[4];
    #pragma unroll
    for (int m = 32; m; m >>= 1) s += __shfl_xor(s, m, 64);
    if ((tid & 63) == 0) red[tid >> 6] = s;
    __syncthreads();
    s = red[0] + red[1] + red[2] + red[3];
    const float rn = 1.f / (s + EPSV);

    for (int i = tid; i < N; i += 256) {
        const int ci = i / 9, tap = i % 9;
        const int ky = tap / 3, kx = tap % 3;
        const float v = fabsf(wrow[i]) * rn;
        const int tf = (2 - ky) * 3 + (2 - kx);
        wBh[((size_t)tap * COUT + co) * CIN + ci] = (_Float16)v;
        wAh[((size_t)tf * CIN + ci) * COUT + co] = (_Float16)v;
    }
}

// ---------------------------------------------------------------------------
// Input prep: xn = relu(x) / (sum_c relu(x) + EPS), per pixel.
// ---------------------------------------------------------------------------
template<int C>
__global__ __launch_bounds__(256) void xn_kernel(const float* __restrict__ in,
                                                 float* __restrict__ xn,
                                                 int npx, int HW)
{
    const int p = blockIdx.x * 256 + threadIdx.x;
    if (p >= npx) return;
    const int b = p / HW, r = p % HW;
    const float* ip = in + (size_t)b * C * HW + r;
    float*       op = xn + (size_t)b * C * HW + r;
    float s = 0.f;
    #pragma unroll 4
    for (int c = 0; c < C; ++c) s += fmaxf(ip[(size_t)c * HW], 0.f);
    const float rs = 1.f / (s + EPSV);
    #pragma unroll 4
    for (int c = 0; c < C; ++c) op[(size_t)c * HW] = fmaxf(ip[(size_t)c * HW], 0.f) * rs;
}

__global__ __launch_bounds__(256) void init_h_kernel(float* __restrict__ h, float* __restrict__ S,
                                                     int nh, int ns, float cval)
{
    const int i = blockIdx.x * 256 + threadIdx.x;
    if (i < nh) h[i] = 1.f;
    if (i < ns) S[i] = cval;
}

__global__ __launch_bounds__(256) void combine_S_kernel(const float* __restrict__ sp,
                                                        float* __restrict__ S, int npx)
{
    const int i = blockIdx.x * 256 + threadIdx.x;
    if (i < npx) S[i] = sp[i] + sp[npx + i];
}

// ---------------------------------------------------------------------------
// MFMA implicit-GEMM 3x3 'same' conv (blocks 1/2).
//   Per WG: 64-pixel tile (TH x TW), 4 waves; wave w owns pixels [16w,16w+16)
//   (one 16-row M fragment) and the WG's WHOLE oc range OCWG = OCg/NSPLIT.
//   K loop: ic chunks of 32 (f16 LDS stage [spatial][40]) x 9 taps; per k-step
//   one ds_read_b128 A-frag + NF global B-frag loads + NF mfma 16x16x32 f16.
//   NORM_IN: staged input scaled by 1/(Sin+eps) per pixel (ratio conv, in=h).
//   !UPDATE: out = aux / (acc+eps).  UPDATE: out *= acc, S via shfl reduce.
// Weights: wgt[tap][n(OCg)][k(ICg)] f16.
// ---------------------------------------------------------------------------
template<int ICg, int OCg, int TH, int TW, int NSPLIT, bool NORM_IN, bool UPDATE>
__global__ __launch_bounds__(256) void mfconv_kernel(
    const float* __restrict__ in, const _Float16* __restrict__ wgt,
    const float* __restrict__ aux, float* __restrict__ out,
    const float* __restrict__ Sin, float* __restrict__ Sout,
    int H, int W, int sstride)
{
    constexpr int MT = 64;
    static_assert(TH * TW == MT, "tile");
    constexpr int OCWG = OCg / NSPLIT;
    constexpr int NF   = OCWG / 16;
    constexpr int HS = TH + 2, WSp = TW + 2, NSP = HS * WSp;
    constexpr int ICB = 32, ICP = ICB + 8, NCH = ICg / ICB;
    constexpr int LS = (NSPLIT == 2) ? 1 : 0;
    static_assert(OCWG % 16 == 0 && ICg % 32 == 0, "dims");

    __shared__ _Float16 in_t[NSP * ICP];
    __shared__ float rS[NORM_IN ? NSP : 1];

    const int tid  = threadIdx.x;
    const int lane = tid & 63, wave = tid >> 6;
    const int kq = lane >> 4, l15 = lane & 15;
    const int split = blockIdx.x & (NSPLIT - 1);
    const int tx = blockIdx.x >> LS;
    const int x0 = tx * TW, y0 = blockIdx.y * TH, b = blockIdx.z;
    const int HW = H * W;
    const int oc0 = split * OCWG;

    if constexpr (NORM_IN) {
        for (int i = tid; i < NSP; i += 256) {
            const int yy = y0 + i / WSp - 1, xx = x0 + i % WSp - 1;
            float sv = 0.f;
            if (yy >= 0 && yy < H && xx >= 0 && xx < W)
                sv = Sin[(size_t)b * HW + (size_t)yy * W + xx];
            rS[i] = 1.f / (sv + EPSV);
        }
    }

    const int m   = wave * 16 + l15;        // this lane's A-row (pixel in tile)
    const int pyl = m / TW, pxl = m % TW;

    f32x4 acc[NF];
    #pragma unroll
    for (int nf = 0; nf < NF; ++nf) acc[nf] = (f32x4){0.f, 0.f, 0.f, 0.f};

    for (int icc = 0; icc < NCH; ++icc) {
        if (icc > 0 || NORM_IN) __syncthreads();
        const int ic0 = icc * ICB;
        // ---- stage 32 input channels as f16 [spatial][ICP] ----
        for (int i = tid; i < 16 * NSP; i += 256) {
            const int k2 = i / NSP, sp = i % NSP;
            const int yy = y0 + sp / WSp - 1, xx = x0 + sp % WSp - 1;
            float v0 = 0.f, v1 = 0.f;
            if (yy >= 0 && yy < H && xx >= 0 && xx < W) {
                const size_t ba = ((size_t)(b * ICg + ic0 + 2 * k2)) * HW + (size_t)yy * W + xx;
                v0 = in[ba]; v1 = in[ba + HW];
                if constexpr (NORM_IN) { const float f = rS[sp]; v0 *= f; v1 *= f; }
            }
            *reinterpret_cast<unsigned*>(&in_t[sp * ICP + 2 * k2]) = pack2f16(v0, v1);
        }
        __syncthreads();

        // ---- 9 taps x (A ds_read + NF B global loads + NF MFMA) ----
        #pragma unroll
        for (int tap = 0; tap < 9; ++tap) {
            const int dy = tap / 3, dx = tap % 3;
            f16x8 bfr[NF];
            #pragma unroll
            for (int nf = 0; nf < NF; ++nf) {
                const int oc = oc0 + nf * 16 + l15;
                bfr[nf] = *reinterpret_cast<const f16x8*>(
                    wgt + ((size_t)tap * OCg + oc) * ICg + ic0 + kq * 8);
            }
            const int sp = (pyl + dy) * WSp + pxl + dx;
            const f16x8 afr = *reinterpret_cast<const f16x8*>(&in_t[sp * ICP + kq * 8]);
            #pragma unroll
            for (int nf = 0; nf < NF; ++nf)
                acc[nf] = __builtin_amdgcn_mfma_f32_16x16x32_f16(afr, bfr[nf], acc[nf], 0, 0, 0);
        }
    }

    // ---- epilogue: lane holds D[row=kq*4+r][col=l15] -> pixel pl+r, oc ----
    const int pl = wave * 16 + kq * 4;
    const int gy = y0 + pl / TW, gxx = x0 + pl % TW;
    const size_t spix = (size_t)gy * W + gxx;
    float s0 = 0.f, s1 = 0.f, s2 = 0.f, s3 = 0.f;
    #pragma unroll
    for (int nf = 0; nf < NF; ++nf) {
        const int oc = oc0 + nf * 16 + l15;
        const size_t idx = ((size_t)(b * OCg + oc)) * HW + spix;
        if constexpr (!UPDATE) {
            const float4 av = *reinterpret_cast<const float4*>(aux + idx);
            float4 ov;
            ov.x = av.x / (acc[nf][0] + EPSV);
            ov.y = av.y / (acc[nf][1] + EPSV);
            ov.z = av.z / (acc[nf][2] + EPSV);
            ov.w = av.w / (acc[nf][3] + EPSV);
            *reinterpret_cast<float4*>(out + idx) = ov;
        } else {
            float4 hv = *reinterpret_cast<float4*>(out + idx);
            hv.x *= acc[nf][0]; hv.y *= acc[nf][1];
            hv.z *= acc[nf][2]; hv.w *= acc[nf][3];
            *reinterpret_cast<float4*>(out + idx) = hv;
            s0 += hv.x; s1 += hv.y; s2 += hv.z; s3 += hv.w;
        }
    }
    if constexpr (UPDATE) {
        #pragma unroll
        for (int mm = 1; mm < 16; mm <<= 1) {
            s0 += __shfl_xor(s0, mm); s1 += __shfl_xor(s1, mm);
            s2 += __shfl_xor(s2, mm); s3 += __shfl_xor(s3, mm);
        }
        if (l15 == 0) {
            float* sp_ = Sout + (size_t)split * sstride + (size_t)b * HW + spix;
            sp_[0] = s0; sp_[1] = s1; sp_[2] = s2; sp_[3] = s3;
        }
    }
}

// ---------------------------------------------------------------------------
// Block-0 ratio conv (IC->3 outputs), fp32 (from R3, unchanged).
// ---------------------------------------------------------------------------
template<int IC, int ICB, int TH, int TW>
__global__ __launch_bounds__(256) void ratio_oc3_kernel(
    const float* __restrict__ h, const float* __restrict__ wA4,
    const float* __restrict__ xn, float* __restrict__ ratio,
    const float* __restrict__ S, int H, int W)
{
    constexpr int NPX = 2;
    constexpr int HS = TH + 2, WSg = TW + 2;
    constexpr int WS = ((WSg + 3) / 4) * 4;
    constexpr int SPR = TW / NPX;
    constexpr int NCH = IC / ICB;
    constexpr int NIF = ICB * HS * WSg;
    constexpr int IREG = (NIF + 255) / 256;
    static_assert(TH * TW == 256 * NPX, "tile size");

    __shared__ float w_l[IC * 36];
    __shared__ float in_t[ICB * HS * WS];
    __shared__ float rS[HS * WSg];

    const int tid  = threadIdx.x;
    const int row  = tid / SPR;
    const int col0 = (tid & (SPR - 1)) * NPX;
    const int x0 = blockIdx.x * TW, y0 = blockIdx.y * TH;
    const int b  = blockIdx.z;
    const int HW = H * W;

    {
        const float4* wsrc = reinterpret_cast<const float4*>(wA4);
        float4* wdst = reinterpret_cast<float4*>(w_l);
        #pragma unroll
        for (int r = 0; r < (IC * 9 + 255) / 256; ++r) {
            const int i = tid + r * 256;
            if (i < IC * 9) wdst[i] = wsrc[i];
        }
    }
    for (int i = tid; i < HS * WSg; i += 256) {
        const int yy = y0 + i / WSg - 1, xx = x0 + i % WSg - 1;
        float sv = 0.f;
        if (yy >= 0 && yy < H && xx >= 0 && xx < W)
            sv = S[(size_t)b * HW + (size_t)yy * W + xx];
        rS[i] = 1.f / (sv + EPSV);
    }

    float pre[IREG];
    #pragma unroll
    for (int r = 0; r < IREG; ++r) {
        const int i = tid + r * 256;
        float v = 0.f;
        if (i < NIF) {
            const int ic = i / (HS * WSg), rr = (i % (HS * WSg)) / WSg, cc = i % WSg;
            const int yy = y0 + rr - 1, xx = x0 + cc - 1;
            if (yy >= 0 && yy < H && xx >= 0 && xx < W)
                v = h[((size_t)(b * IC + ic)) * HW + (size_t)yy * W + xx];
        }
        pre[r] = v;
    }
    __syncthreads();
    #pragma unroll
    for (int r = 0; r < IREG; ++r) {
        const int i = tid + r * 256;
        if (i < NIF) {
            const int ic = i / (HS * WSg), rr = (i % (HS * WSg)) / WSg, cc = i % WSg;
            in_t[ic * (HS * WS) + rr * WS + cc] = pre[r] * rS[rr * WSg + cc];
        }
    }
    __syncthreads();

    float acc0[NPX], acc1[NPX], acc2[NPX];
    #pragma unroll
    for (int p = 0; p < NPX; ++p) { acc0[p] = 0.f; acc1[p] = 0.f; acc2[p] = 0.f; }

    for (int c = 0; c < NCH; ++c) {
        if (c + 1 < NCH) {
            #pragma unroll
            for (int r = 0; r < IREG; ++r) {
                const int i = tid + r * 256;
                float v = 0.f;
                if (i < NIF) {
                    const int ic = i / (HS * WSg), rr = (i % (HS * WSg)) / WSg, cc = i % WSg;
                    const int yy = y0 + rr - 1, xx = x0 + cc - 1;
                    if (yy >= 0 && yy < H && xx >= 0 && xx < W)
                        v = h[((size_t)(b * IC + (c + 1) * ICB + ic)) * HW + (size_t)yy * W + xx];
                }
                pre[r] = v;
            }
        }
        for (int ic = 0; ic < ICB; ++ic) {
            const float* ib = in_t + ic * (HS * WS) + row * WS + col0;
            float win[3][4];
            #pragma unroll
            for (int dy = 0; dy < 3; ++dy) {
                const float2 a = *reinterpret_cast<const float2*>(ib + dy * WS);
                const float2 bb = *reinterpret_cast<const float2*>(ib + dy * WS + 2);
                win[dy][0] = a.x; win[dy][1] = a.y; win[dy][2] = bb.x; win[dy][3] = bb.y;
            }
            const float* wb = w_l + (c * ICB + ic) * 36;
            #pragma unroll
            for (int t = 0; t < 9; ++t) {
                const float4 wv = *reinterpret_cast<const float4*>(wb + t * 4);
                const int ky = t / 3, kx = t % 3;
                #pragma unroll
                for (int p = 0; p < NPX; ++p) {
                    const float v = win[ky][kx + p];
                    acc0[p] = fmaf(v, wv.x, acc0[p]);
                    acc1[p] = fmaf(v, wv.y, acc1[p]);
                    acc2[p] = fmaf(v, wv.z, acc2[p]);
                }
            }
        }
        __syncthreads();
        if (c + 1 < NCH) {
            #pragma unroll
            for (int r = 0; r < IREG; ++r) {
                const int i = tid + r * 256;
                if (i < NIF) {
                    const int ic = i / (HS * WSg), rr = (i % (HS * WSg)) / WSg, cc = i % WSg;
                    in_t[ic * (HS * WS) + rr * WS + cc] = pre[r] * rS[rr * WSg + cc];
                }
            }
        }
        __syncthreads();
    }

    const int gy = y0 + row, gx0 = x0 + col0;
    const size_t p0 = ((size_t)(b * 3)) * HW + (size_t)gy * W + gx0;
    float* accs[3] = {acc0, acc1, acc2};
    #pragma unroll
    for (int oc = 0; oc < 3; ++oc) {
        const size_t idx = p0 + (size_t)oc * HW;
        const float2 av = *reinterpret_cast<const float2*>(xn + idx);
        float2 ov;
        ov.x = av.x / (accs[oc][0] + EPSV);
        ov.y = av.y / (accs[oc][1] + EPSV);
        *reinterpret_cast<float2*>(ratio + idx) = ov;
    }
}

// ---------------------------------------------------------------------------
// Block-0 update conv (3 -> 64), fp32 register-tiled (single chunk).
// ---------------------------------------------------------------------------
template<int IC, int OC, int TH, int TW, int PXT, int NPX, int NOC, int ICB,
         bool NORM_IN, bool UPDATE>
__global__ __launch_bounds__(256) void conv3v3_kernel(
    const float* __restrict__ in, const float* __restrict__ wgt,
    const float* __restrict__ aux, float* __restrict__ out,
    const float* __restrict__ Sin, float* __restrict__ Sout,
    int H, int W)
{
    constexpr int OCG = 256 / PXT;
    constexpr int TPX = TH * TW;
    constexpr int SPR = TW / NPX;
    constexpr int HS  = TH + 2;
    constexpr int WSg = TW + 2;
    constexpr int WS  = ((WSg + 3) / 4) * 4;
    constexpr int NCH = IC / ICB;
    constexpr int NIF = ICB * HS * WSg;
    constexpr int IREG = (NIF + 255) / 256;
    constexpr int NWF = ICB * 9 * OC;
    constexpr int NW4 = NWF / 4;
    constexpr int WREG = (NW4 + 255) / 256;
    static_assert(TPX == PXT * NPX, "tile mismatch");
    static_assert(OCG * NOC >= OC, "oc coverage");
    static_assert(NPX == 4 && NOC % 4 == 0 && NWF % 4 == 0 && IC % ICB == 0, "cfg");

    __shared__ float in_t[ICB * HS * WS];
    __shared__ float w_t[NWF];
    __shared__ float rS[NORM_IN ? HS * WSg : 1];
    __shared__ float red[UPDATE ? OCG * TPX : 1];

    const int tid  = threadIdx.x;
    const int pxs  = tid % PXT;
    const int ocg  = tid / PXT;
    const int row  = pxs / SPR;
    const int col0 = (pxs % SPR) * NPX;
    const int x0 = blockIdx.x * TW, y0 = blockIdx.y * TH;
    const int b  = blockIdx.z;
    const int HW = H * W;

    if constexpr (NORM_IN) {
        for (int i = tid; i < HS * WSg; i += 256) {
            const int yy = y0 + i / WSg - 1, xx = x0 + i % WSg - 1;
            float sv = 0.f;
            if (yy >= 0 && yy < H && xx >= 0 && xx < W)
                sv = Sin[(size_t)b * HW + (size_t)yy * W + xx];
            rS[i] = 1.f / (sv + EPSV);
        }
    }

    float ipre[IREG];
    float4 wpre[WREG];
    const float4* wsrc4 = reinterpret_cast<const float4*>(wgt);

    #pragma unroll
    for (int r = 0; r < IREG; ++r) {
        const int i = tid + r * 256;
        float v = 0.f;
        if (i < NIF) {
            const int ic = i / (HS * WSg), rr = (i % (HS * WSg)) / WSg, cc = i % WSg;
            const int yy = y0 + rr - 1, xx = x0 + cc - 1;
            if (yy >= 0 && yy < H && xx >= 0 && xx < W)
                v = in[((size_t)(b * IC + ic)) * HW + (size_t)yy * W + xx];
        }
        ipre[r] = v;
    }
    #pragma unroll
    for (int r = 0; r < WREG; ++r) {
        const int i = tid + r * 256;
        if (i < NW4) wpre[r] = wsrc4[i];
    }
    __syncthreads();
    #pragma unroll
    for (int r = 0; r < IREG; ++r) {
        const int i = tid + r * 256;
        if (i < NIF) {
            const int ic = i / (HS * WSg), rr = (i % (HS * WSg)) / WSg, cc = i % WSg;
            float v = ipre[r];
            if constexpr (NORM_IN) v *= rS[rr * WSg + cc];
            in_t[ic * (HS * WS) + rr * WS + cc] = v;
        }
    }
    {
        float4* wdst = reinterpret_cast<float4*>(w_t);
        #pragma unroll
        for (int r = 0; r < WREG; ++r) {
            const int i = tid + r * 256;
            if (i < NW4) wdst[i] = wpre[r];
        }
    }
    __syncthreads();

    float acc[NOC][NPX];
    #pragma unroll
    for (int j = 0; j < NOC; ++j)
        #pragma unroll
        for (int p = 0; p < NPX; ++p) acc[j][p] = 0.f;

    for (int c = 0; c < NCH; ++c) {
        if (c + 1 < NCH) {
            #pragma unroll
            for (int r = 0; r < IREG; ++r) {
                const int i = tid + r * 256;
                float v = 0.f;
                if (i < NIF) {
                    const int ic = i / (HS * WSg), rr = (i % (HS * WSg)) / WSg, cc = i % WSg;
                    const int yy = y0 + rr - 1, xx = x0 + cc - 1;
                    if (yy >= 0 && yy < H && xx >= 0 && xx < W)
                        v = in[((size_t)(b * IC + (c + 1) * ICB + ic)) * HW + (size_t)yy * W + xx];
                }
                ipre[r] = v;
            }
            #pragma unroll
            for (int r = 0; r < WREG; ++r) {
                const int i = tid + r * 256;
                if (i < NW4) wpre[r] = wsrc4[(size_t)(c + 1) * NW4 + i];
            }
        }
        for (int ic = 0; ic < ICB; ++ic) {
            const float* wbase = w_t + ic * 9 * OC;
            const float* ibase = in_t + ic * (HS * WS) + row * WS + col0;

            float win[3][6];
            #pragma unroll
            for (int dy = 0; dy < 3; ++dy) {
                const float* rp = ibase + dy * WS;
                const float4 a = *reinterpret_cast<const float4*>(rp);
                const float2 cxy = *reinterpret_cast<const float2*>(rp + 4);
                win[dy][0] = a.x; win[dy][1] = a.y; win[dy][2] = a.z; win[dy][3] = a.w;
                win[dy][4] = cxy.x; win[dy][5] = cxy.y;
            }
            #pragma unroll
            for (int t = 0; t < 9; ++t) {
                const int ky = t / 3, kx = t % 3;
                #pragma unroll
                for (int j4 = 0; j4 < NOC / 4; ++j4) {
                    const float4 wv = *reinterpret_cast<const float4*>(
                        wbase + t * OC + ocg * NOC + j4 * 4);
                    #pragma unroll
                    for (int p = 0; p < NPX; ++p) {
                        const float v = win[ky][kx + p];
                        acc[j4 * 4 + 0][p] = fmaf(v, wv.x, acc[j4 * 4 + 0][p]);
                        acc[j4 * 4 + 1][p] = fmaf(v, wv.y, acc[j4 * 4 + 1][p]);
                        acc[j4 * 4 + 2][p] = fmaf(v, wv.z, acc[j4 * 4 + 2][p]);
                        acc[j4 * 4 + 3][p] = fmaf(v, wv.w, acc[j4 * 4 + 3][p]);
                    }
                }
            }
        }
        __syncthreads();
        if (c + 1 < NCH) {
            #pragma unroll
            for (int r = 0; r < IREG; ++r) {
                const int i = tid + r * 256;
                if (i < NIF) {
                    const int ic = i / (HS * WSg), rr = (i % (HS * WSg)) / WSg, cc = i % WSg;
                    float v = ipre[r];
                    if constexpr (NORM_IN) v *= rS[rr * WSg + cc];
                    in_t[ic * (HS * WS) + rr * WS + cc] = v;
                }
            }
            float4* wdst = reinterpret_cast<float4*>(w_t);
            #pragma unroll
            for (int r = 0; r < WREG; ++r) {
                const int i = tid + r * 256;
                if (i < NW4) wdst[i] = wpre[r];
            }
            __syncthreads();
        }
    }

    const int gy = y0 + row, gx0 = x0 + col0;

    if constexpr (!UPDATE) {
        #pragma unroll
        for (int j = 0; j < NOC; ++j) {
            const int oc = ocg * NOC + j;
            if constexpr (OCG * NOC > OC) { if (oc >= OC) continue; }
            const size_t idx = ((size_t)(b * OC + oc)) * HW + (size_t)gy * W + gx0;
            const float4 av = *reinterpret_cast<const float4*>(aux + idx);
            float4 ov;
            ov.x = av.x / (acc[j][0] + EPSV);
            ov.y = av.y / (acc[j][1] + EPSV);
            ov.z = av.z / (acc[j][2] + EPSV);
            ov.w = av.w / (acc[j][3] + EPSV);
            *reinterpret_cast<float4*>(out + idx) = ov;
        }
    } else {
        float psum[NPX];
        #pragma unroll
        for (int p = 0; p < NPX; ++p) psum[p] = 0.f;
        #pragma unroll
        for (int j = 0; j < NOC; ++j) {
            const int oc = ocg * NOC + j;
            if constexpr (OCG * NOC > OC) { if (oc >= OC) continue; }
            const size_t idx = ((size_t)(b * OC + oc)) * HW + (size_t)gy * W + gx0;
            float4 hv = *reinterpret_cast<const float4*>(out + idx);
            hv.x *= acc[j][0]; hv.y *= acc[j][1]; hv.z *= acc[j][2]; hv.w *= acc[j][3];
            psum[0] += hv.x; psum[1] += hv.y; psum[2] += hv.z; psum[3] += hv.w;
            *reinterpret_cast<float4*>(out + idx) = hv;
        }
        const int pix0 = row * TW + col0;
        #pragma unroll
        for (int p = 0; p < NPX; ++p) red[ocg * TPX + pix0 + p] = psum[p];
        __syncthreads();
        if (tid < TPX) {
            float s = 0.f;
            #pragma unroll
            for (int g = 0; g < OCG; ++g) s += red[g * TPX + tid];
            const int py = tid / TW, pxx = tid % TW;
            Sout[(size_t)b * HW + (size_t)(y0 + py) * W + (x0 + pxx)] = s;
        }
    }
}

// ---------------------------------------------------------------------------
// Post: 1x1 conv + relu + BN stats + BN + avgpool (fp32, from R3).
// ---------------------------------------------------------------------------
template<int C>
__global__ __launch_bounds__(256) void post1_kernel(
    const float* __restrict__ h, const float* __restrict__ S,
    const float* __restrict__ w1, const float* __restrict__ bias,
    float* __restrict__ part, int H, int W)
{
    constexpr int NOC = C / 8;
    __shared__ float h_t[C * 32];
    __shared__ float sS[32];
    const int tid = threadIdx.x;
    const int px = tid & 31, ocg = tid >> 5;
    const int x0 = blockIdx.x * 8, y0 = blockIdx.y * 4, b = blockIdx.z;
    const int HW = H * W;

    if (tid < 32) {
        const int gy = y0 + (tid >> 3), gx = x0 + (tid & 7);
        sS[tid] = 1.f / (S[(size_t)b * HW + gy * W + gx] + EPSV);
    }
    __syncthreads();
    for (int i = tid; i < C * 32; i += 256) {
        const int c = i >> 5, p = i & 31;
        const int gy = y0 + (p >> 3), gx = x0 + (p & 7);
        h_t[i] = h[((size_t)(b * C + c)) * HW + gy * W + gx] * sS[p];
    }
    __syncthreads();

    const int wgid = (b * gridDim.y + blockIdx.y) * gridDim.x + blockIdx.x;
    for (int j = 0; j < NOC; ++j) {
        const int oc = ocg * NOC + j;
        const float* wrow = w1 + (size_t)oc * C;
        float a = 0.f;
        #pragma unroll 4
        for (int co = 0; co < C; ++co) a = fmaf(wrow[co], h_t[co * 32 + px], a);
        float y  = fmaxf(a + bias[oc], 0.f);
        float y2 = y * y;
        #pragma unroll
        for (int m = 16; m; m >>= 1) { y += __shfl_xor(y, m, 32); y2 += __shfl_xor(y2, m, 32); }
        if (px == 0) {
            part[((size_t)wgid * C + oc) * 2 + 0] = y;
            part[((size_t)wgid * C + oc) * 2 + 1] = y2;
        }
    }
}

template<int C>
__global__ __launch_bounds__(256) void stats_kernel(const float* __restrict__ part, int nwg, float invM,
                                                    const float* __restrict__ gamma,
                                                    const float* __restrict__ beta,
                                                    float* __restrict__ stats)
{
    const int oc = blockIdx.x;
    const int tid = threadIdx.x;
    float s1 = 0.f, s2 = 0.f;
    for (int w = tid; w < nwg; w += 256) {
        s1 += part[((size_t)w * C + oc) * 2 + 0];
        s2 += part[((size_t)w * C + oc) * 2 + 1];
    }
    __shared__ float r1[4], r2[4];
    #pragma unroll
    for (int m = 32; m; m >>= 1) { s1 += __shfl_xor(s1, m, 64); s2 += __shfl_xor(s2, m, 64); }
    if ((tid & 63) == 0) { r1[tid >> 6] = s1; r2[tid >> 6] = s2; }
    __syncthreads();
    if (tid == 0) {
        s1 = r1[0] + r1[1] + r1[2] + r1[3];
        s2 = r2[0] + r2[1] + r2[2] + r2[3];
        const float mean = s1 * invM;
        const float var  = s2 * invM - mean * mean;
        const float rstd = rsqrtf(var + BNEPS);
        const float scale = gamma[oc] * rstd;
        stats[oc]     = scale;
        stats[C + oc] = beta[oc] - mean * scale;
    }
}

template<int C>
__global__ __launch_bounds__(256) void post2_kernel(
    const float* __restrict__ h, const float* __restrict__ S,
    const float* __restrict__ w1, const float* __restrict__ bias,
    const float* __restrict__ stats, float* __restrict__ out, int H, int W)
{
    constexpr int NOC = C / 8;
    __shared__ float h_t[C * 32];
    __shared__ float sS[32];
    __shared__ float y_t[8 * 32];
    const int tid = threadIdx.x;
    const int px = tid & 31, ocg = tid >> 5;
    const int x0 = blockIdx.x * 8, y0 = blockIdx.y * 4, b = blockIdx.z;
    const int HW = H * W;

    if (tid < 32) {
        const int gy = y0 + (tid >> 3), gx = x0 + (tid & 7);
        sS[tid] = 1.f / (S[(size_t)b * HW + gy * W + gx] + EPSV);
    }
    __syncthreads();
    for (int i = tid; i < C * 32; i += 256) {
        const int c = i >> 5, p = i & 31;
        const int gy = y0 + (p >> 3), gx = x0 + (p & 7);
        h_t[i] = h[((size_t)(b * C + c)) * HW + gy * W + gx] * sS[p];
    }
    __syncthreads();

    const int Ho = H >> 1, Wo = W >> 1;
    for (int j = 0; j < NOC; ++j) {
        const int oc = ocg * NOC + j;
        const float* wrow = w1 + (size_t)oc * C;
        float a = 0.f;
        #pragma unroll 4
        for (int co = 0; co < C; ++co) a = fmaf(wrow[co], h_t[co * 32 + px], a);
        float y = fmaxf(a + bias[oc], 0.f);
        y = y * stats[oc] + stats[C + oc];
        y_t[ocg * 32 + px] = y;
        __syncthreads();
        if (tid < 64) {
            const int o8 = tid >> 3, pp = tid & 7;
            const int ppy = pp >> 2, ppx = pp & 3;
            const float* yr = y_t + o8 * 32 + ppy * 16 + ppx * 2;
            const float v = (yr[0] + yr[1] + yr[8] + yr[9]) * 0.25f;
            const int oco = o8 * NOC + j;
            out[((size_t)(b * C + oco)) * Ho * Wo + ((blockIdx.y << 1) + ppy) * Wo
                + (blockIdx.x << 2) + ppx] = v;
        }
        __syncthreads();
    }
}

// ---------------------------------------------------------------------------
// Drivers
// ---------------------------------------------------------------------------
static void post_phase(const float* h, const float* S, const float* w1, const float* bias,
                       const float* gamma, const float* beta, float* pout,
                       float* part, float* stats, int C, int H, int W, hipStream_t stream)
{
    const int B = 16, HW = H * W;
    dim3 pg(W / 8, H / 4, B);
    const int nwg = pg.x * pg.y * pg.z;
    if (C == 64) {
        post1_kernel<64><<<pg, 256, 0, stream>>>(h, S, w1, bias, part, H, W);
        stats_kernel<64><<<64, 256, 0, stream>>>(part, nwg, 1.0f / (float)(B * HW), gamma, beta, stats);
        post2_kernel<64><<<pg, 256, 0, stream>>>(h, S, w1, bias, stats, pout, H, W);
    } else if (C == 128) {
        post1_kernel<128><<<pg, 256, 0, stream>>>(h, S, w1, bias, part, H, W);
        stats_kernel<128><<<128, 256, 0, stream>>>(part, nwg, 1.0f / (float)(B * HW), gamma, beta, stats);
        post2_kernel<128><<<pg, 256, 0, stream>>>(h, S, w1, bias, stats, pout, H, W);
    } else {
        post1_kernel<256><<<pg, 256, 0, stream>>>(h, S, w1, bias, part, H, W);
        stats_kernel<256><<<256, 256, 0, stream>>>(part, nwg, 1.0f / (float)(B * HW), gamma, beta, stats);
        post2_kernel<256><<<pg, 256, 0, stream>>>(h, S, w1, bias, stats, pout, H, W);
    }
}

extern "C" void kernel_launch(void* const* d_in, const int* in_sizes, int n_in,
                              void* d_out, int out_size, void* d_ws, size_t ws_size,
                              hipStream_t stream)
{
    const float* x = (const float*)d_in[0];
    float* ws    = (float*)d_ws;
    float* h     = ws;                    // 16,777,216
    float* xn    = h     + 16777216;      //  4,194,304
    float* ratio = xn    + 4194304;       //  4,194,304
    float* out0  = ratio + 4194304;       //  4,194,304
    float* out1  = out0  + 4194304;       //  2,097,152
    float* S     = out1  + 2097152;       //    262,144
    float* wA    = S     + 262144;        //      4,096 (block0 fp32)
    float* wB    = wA    + 4096;          //      4,096 (block0 fp32)
    float* part  = wB    + 4096;          //  1,048,576 (also Spart for block2)
    float* stats = part  + 1048576;       //        512
    _Float16* wAh = (_Float16*)(stats + 512);       // 294,912 f16
    _Float16* wBh = wAh + 294912;                   // 294,912 f16

    const int B = 16;

    // ---------------- Block 0: Cin=3, Cout=64, 128x128 ----------------
    {
        const int H = 128, W = 128, HW = H * W;
        prep_w_kernel<3, 64, 4><<<64, 256, 0, stream>>>((const float*)d_in[1], wA, wB);
        const int npx = B * HW;
        xn_kernel<3><<<(npx + 255) / 256, 256, 0, stream>>>(x, xn, npx, HW);
        const int nh = B * 64 * HW;
        init_h_kernel<<<(nh + 255) / 256, 256, 0, stream>>>(h, S, nh, npx, 64.f);
        for (int it = 0; it < 5; ++it) {
            ratio_oc3_kernel<64, 8, 32, 16>
                <<<dim3(W / 16, H / 32, B), 256, 0, stream>>>(h, wA, xn, ratio, S, H, W);
            conv3v3_kernel<3, 64, 16, 16, 64, 4, 16, 3, false, true>
                <<<dim3(W / 16, H / 16, B), 256, 0, stream>>>(ratio, wB, nullptr, h, nullptr, S, H, W);
        }
        post_phase(h, S, (const float*)d_in[2], (const float*)d_in[3],
                   (const float*)d_in[4], (const float*)d_in[5], out0, part, stats, 64, H, W, stream);
    }

    // ---------------- Block 1: Cin=64, Cout=128, 64x64 (MFMA) ----------------
    {
        const int H = 64, W = 64, HW = H * W;
        prep_w_f16_kernel<64, 128><<<128, 256, 0, stream>>>((const float*)d_in[6], wAh, wBh);
        const int npx = B * HW;
        xn_kernel<64><<<(npx + 255) / 256, 256, 0, stream>>>(out0, xn, npx, HW);
        const int nh = B * 128 * HW;
        init_h_kernel<<<(nh + 255) / 256, 256, 0, stream>>>(h, S, nh, npx, 128.f);
        for (int it = 0; it < 5; ++it) {
            // ratio = xn / conv(h/S): K=128(co), N=64(ci)
            mfconv_kernel<128, 64, 4, 16, 1, true, false>
                <<<dim3(4, 16, B), 256, 0, stream>>>(h, wAh, xn, ratio, S, nullptr, H, W, 0);
            // h *= conv(ratio): K=64(ci), N=128(co); S direct
            mfconv_kernel<64, 128, 4, 16, 1, false, true>
                <<<dim3(4, 16, B), 256, 0, stream>>>(ratio, wBh, nullptr, h, nullptr, S, H, W, 0);
        }
        post_phase(h, S, (const float*)d_in[7], (const float*)d_in[8],
                   (const float*)d_in[9], (const float*)d_in[10], out1, part, stats, 128, H, W, stream);
    }

    // ---------------- Block 2: Cin=128, Cout=256, 32x32 (MFMA) ----------------
    {
        const int H = 32, W = 32, HW = H * W;
        prep_w_f16_kernel<128, 256><<<256, 256, 0, stream>>>((const float*)d_in[11], wAh, wBh);
        const int npx = B * HW;
        xn_kernel<128><<<(npx + 255) / 256, 256, 0, stream>>>(out1, xn, npx, HW);
        const int nh = B * 256 * HW;
        init_h_kernel<<<(nh + 255) / 256, 256, 0, stream>>>(h, S, nh, npx, 256.f);
        for (int it = 0; it < 5; ++it) {
            // ratio: K=256(co), N=128(ci), OC split across 2 WGs
            mfconv_kernel<256, 128, 8, 8, 2, true, false>
                <<<dim3(8, 4, B), 256, 0, stream>>>(h, wAh, xn, ratio, S, nullptr, H, W, 0);
            // update: K=128(ci), N=256(co), split -> partial S in `part`
            mfconv_kernel<128, 256, 8, 8, 2, false, true>
                <<<dim3(8, 4, B), 256, 0, stream>>>(ratio, wBh, nullptr, h, nullptr, part, H, W, npx);
            combine_S_kernel<<<(npx + 255) / 256, 256, 0, stream>>>(part, S, npx);
        }
        post_phase(h, S, (const float*)d_in[12], (const float*)d_in[13],
                   (const float*)d_in[14], (const float*)d_in[15], (float*)d_out, part, stats, 256, H, W, stream);
    }
}

// Round 5
// 2648.630 us; speedup vs baseline: 2.8946x; 1.3291x over previous
//
#include <hip/hip_runtime.h>

#define EPSV  1e-20f
#define BNEPS 1e-5f

typedef _Float16 f16x8 __attribute__((ext_vector_type(8)));
typedef _Float16 f16x4 __attribute__((ext_vector_type(4)));
typedef float    f32x4 __attribute__((ext_vector_type(4)));

__device__ inline unsigned pack2f16(float a, float b) {
    unsigned short ua = __builtin_bit_cast(unsigned short, (_Float16)a);
    unsigned short ub = __builtin_bit_cast(unsigned short, (_Float16)b);
    return ((unsigned)ub << 16) | ua;
}

// ---------------------------------------------------------------------------
// Weight prep (block0, fp32): wn = |w| / (sum + EPS).
// ---------------------------------------------------------------------------
template<int CIN, int COUT, int OCA>
__global__ __launch_bounds__(256) void prep_w_kernel(const float* __restrict__ w,
                                                     float* __restrict__ wA,
                                                     float* __restrict__ wB)
{
    const int co  = blockIdx.x;
    const int tid = threadIdx.x;
    const int N   = CIN * 9;
    const float* wrow = w + (size_t)co * N;

    float s = 0.f;
    for (int i = tid; i < N; i += 256) s += fabsf(wrow[i]);
    __shared__ float red[4];
    #pragma unroll
    for (int m = 32; m; m >>= 1) s += __shfl_xor(s, m, 64);
    if ((tid & 63) == 0) red[tid >> 6] = s;
    __syncthreads();
    s = red[0] + red[1] + red[2] + red[3];
    const float rn = 1.f / (s + EPSV);

    for (int i = tid; i < N; i += 256) {
        const int ci = i / 9, tap = i % 9;
        const int ky = tap / 3, kx = tap % 3;
        const float v = fabsf(wrow[i]) * rn;
        wB[((size_t)ci * 9 + tap) * COUT + co] = v;
        wA[((size_t)co * 9 + (2 - ky) * 3 + (2 - kx)) * OCA + ci] = v;
    }
}

// ---------------------------------------------------------------------------
// Weight prep (blocks 1/2, f16 GEMM layouts):
//   wBh[tap][co][ci]   (update conv: n=co, k=ci)
//   wAh[tap'][ci][co]  (ratio  conv: n=ci, k=co)
// ---------------------------------------------------------------------------
template<int CIN, int COUT>
__global__ __launch_bounds__(256) void prep_w_f16_kernel(const float* __restrict__ w,
                                                         _Float16* __restrict__ wAh,
                                                         _Float16* __restrict__ wBh)
{
    const int co  = blockIdx.x;
    const int tid = threadIdx.x;
    const int N   = CIN * 9;
    const float* wrow = w + (size_t)co * N;

    float s = 0.f;
    for (int i = tid; i < N; i += 256) s += fabsf(wrow[i]);
    __shared__ float red[4];
    #pragma unroll
    for (int m = 32; m; m >>= 1) s += __shfl_xor(s, m, 64);
    if ((tid & 63) == 0) red[tid >> 6] = s;
    __syncthreads();
    s = red[0] + red[1] + red[2] + red[3];
    const float rn = 1.f / (s + EPSV);

    for (int i = tid; i < N; i += 256) {
        const int ci = i / 9, tap = i % 9;
        const int ky = tap / 3, kx = tap % 3;
        const float v = fabsf(wrow[i]) * rn;
        const int tf = (2 - ky) * 3 + (2 - kx);
        wBh[((size_t)tap * COUT + co) * CIN + ci] = (_Float16)v;
        wAh[((size_t)tf * CIN + ci) * COUT + co] = (_Float16)v;
    }
}

__global__ __launch_bounds__(256) void prep_w1h_kernel(const float* __restrict__ w1,
                                                       _Float16* __restrict__ w1h, int n)
{
    const int i = blockIdx.x * 256 + threadIdx.x;
    if (i < n) w1h[i] = (_Float16)w1[i];
}

// ---------------------------------------------------------------------------
// Input prep: xn = relu(x) / (sum_c relu(x) + EPS), per pixel.
// ---------------------------------------------------------------------------
template<int C>
__global__ __launch_bounds__(256) void xn_kernel(const float* __restrict__ in,
                                                 float* __restrict__ xn,
                                                 int npx, int HW)
{
    const int p = blockIdx.x * 256 + threadIdx.x;
    if (p >= npx) return;
    const int b = p / HW, r = p % HW;
    const float* ip = in + (size_t)b * C * HW + r;
    float*       op = xn + (size_t)b * C * HW + r;
    float s = 0.f;
    #pragma unroll 4
    for (int c = 0; c < C; ++c) s += fmaxf(ip[(size_t)c * HW], 0.f);
    const float rs = 1.f / (s + EPSV);
    #pragma unroll 4
    for (int c = 0; c < C; ++c) op[(size_t)c * HW] = fmaxf(ip[(size_t)c * HW], 0.f) * rs;
}

__global__ __launch_bounds__(256) void init_h_kernel(float* __restrict__ h, float* __restrict__ S,
                                                     int nh, int ns, float cval)
{
    const int i = blockIdx.x * 256 + threadIdx.x;
    if (i < nh) h[i] = 1.f;
    if (i < ns) S[i] = cval;
}

__global__ __launch_bounds__(256) void combine_S_kernel(const float* __restrict__ sp,
                                                        float* __restrict__ S, int npx)
{
    const int i = blockIdx.x * 256 + threadIdx.x;
    if (i < npx) S[i] = sp[i] + sp[npx + i];
}

// ---------------------------------------------------------------------------
// MFMA implicit-GEMM 3x3 'same' conv (blocks 1/2) — from R4, unchanged.
// ---------------------------------------------------------------------------
template<int ICg, int OCg, int TH, int TW, int NSPLIT, bool NORM_IN, bool UPDATE>
__global__ __launch_bounds__(256) void mfconv_kernel(
    const float* __restrict__ in, const _Float16* __restrict__ wgt,
    const float* __restrict__ aux, float* __restrict__ out,
    const float* __restrict__ Sin, float* __restrict__ Sout,
    int H, int W, int sstride)
{
    constexpr int MT = 64;
    static_assert(TH * TW == MT, "tile");
    constexpr int OCWG = OCg / NSPLIT;
    constexpr int NF   = OCWG / 16;
    constexpr int HS = TH + 2, WSp = TW + 2, NSP = HS * WSp;
    constexpr int ICB = 32, ICP = ICB + 8, NCH = ICg / ICB;
    constexpr int LS = (NSPLIT == 2) ? 1 : 0;
    static_assert(OCWG % 16 == 0 && ICg % 32 == 0, "dims");

    __shared__ _Float16 in_t[NSP * ICP];
    __shared__ float rS[NORM_IN ? NSP : 1];

    const int tid  = threadIdx.x;
    const int lane = tid & 63, wave = tid >> 6;
    const int kq = lane >> 4, l15 = lane & 15;
    const int split = blockIdx.x & (NSPLIT - 1);
    const int tx = blockIdx.x >> LS;
    const int x0 = tx * TW, y0 = blockIdx.y * TH, b = blockIdx.z;
    const int HW = H * W;
    const int oc0 = split * OCWG;

    if constexpr (NORM_IN) {
        for (int i = tid; i < NSP; i += 256) {
            const int yy = y0 + i / WSp - 1, xx = x0 + i % WSp - 1;
            float sv = 0.f;
            if (yy >= 0 && yy < H && xx >= 0 && xx < W)
                sv = Sin[(size_t)b * HW + (size_t)yy * W + xx];
            rS[i] = 1.f / (sv + EPSV);
        }
    }

    const int m   = wave * 16 + l15;
    const int pyl = m / TW, pxl = m % TW;

    f32x4 acc[NF];
    #pragma unroll
    for (int nf = 0; nf < NF; ++nf) acc[nf] = (f32x4){0.f, 0.f, 0.f, 0.f};

    for (int icc = 0; icc < NCH; ++icc) {
        if (icc > 0 || NORM_IN) __syncthreads();
        const int ic0 = icc * ICB;
        for (int i = tid; i < 16 * NSP; i += 256) {
            const int k2 = i / NSP, sp = i % NSP;
            const int yy = y0 + sp / WSp - 1, xx = x0 + sp % WSp - 1;
            float v0 = 0.f, v1 = 0.f;
            if (yy >= 0 && yy < H && xx >= 0 && xx < W) {
                const size_t ba = ((size_t)(b * ICg + ic0 + 2 * k2)) * HW + (size_t)yy * W + xx;
                v0 = in[ba]; v1 = in[ba + HW];
                if constexpr (NORM_IN) { const float f = rS[sp]; v0 *= f; v1 *= f; }
            }
            *reinterpret_cast<unsigned*>(&in_t[sp * ICP + 2 * k2]) = pack2f16(v0, v1);
        }
        __syncthreads();

        #pragma unroll
        for (int tap = 0; tap < 9; ++tap) {
            const int dy = tap / 3, dx = tap % 3;
            f16x8 bfr[NF];
            #pragma unroll
            for (int nf = 0; nf < NF; ++nf) {
                const int oc = oc0 + nf * 16 + l15;
                bfr[nf] = *reinterpret_cast<const f16x8*>(
                    wgt + ((size_t)tap * OCg + oc) * ICg + ic0 + kq * 8);
            }
            const int sp = (pyl + dy) * WSp + pxl + dx;
            const f16x8 afr = *reinterpret_cast<const f16x8*>(&in_t[sp * ICP + kq * 8]);
            #pragma unroll
            for (int nf = 0; nf < NF; ++nf)
                acc[nf] = __builtin_amdgcn_mfma_f32_16x16x32_f16(afr, bfr[nf], acc[nf], 0, 0, 0);
        }
    }

    const int pl = wave * 16 + kq * 4;
    const int gy = y0 + pl / TW, gxx = x0 + pl % TW;
    const size_t spix = (size_t)gy * W + gxx;
    float s0 = 0.f, s1 = 0.f, s2 = 0.f, s3 = 0.f;
    #pragma unroll
    for (int nf = 0; nf < NF; ++nf) {
        const int oc = oc0 + nf * 16 + l15;
        const size_t idx = ((size_t)(b * OCg + oc)) * HW + spix;
        if constexpr (!UPDATE) {
            const float4 av = *reinterpret_cast<const float4*>(aux + idx);
            float4 ov;
            ov.x = av.x / (acc[nf][0] + EPSV);
            ov.y = av.y / (acc[nf][1] + EPSV);
            ov.z = av.z / (acc[nf][2] + EPSV);
            ov.w = av.w / (acc[nf][3] + EPSV);
            *reinterpret_cast<float4*>(out + idx) = ov;
        } else {
            float4 hv = *reinterpret_cast<float4*>(out + idx);
            hv.x *= acc[nf][0]; hv.y *= acc[nf][1];
            hv.z *= acc[nf][2]; hv.w *= acc[nf][3];
            *reinterpret_cast<float4*>(out + idx) = hv;
            s0 += hv.x; s1 += hv.y; s2 += hv.z; s3 += hv.w;
        }
    }
    if constexpr (UPDATE) {
        #pragma unroll
        for (int mm = 1; mm < 16; mm <<= 1) {
            s0 += __shfl_xor(s0, mm); s1 += __shfl_xor(s1, mm);
            s2 += __shfl_xor(s2, mm); s3 += __shfl_xor(s3, mm);
        }
        if (l15 == 0) {
            float* sp_ = Sout + (size_t)split * sstride + (size_t)b * HW + spix;
            sp_[0] = s0; sp_[1] = s1; sp_[2] = s2; sp_[3] = s3;
        }
    }
}

// ---------------------------------------------------------------------------
// Block-0 ratio conv (IC->3 outputs), fp32 — from R3, unchanged.
// ---------------------------------------------------------------------------
template<int IC, int ICB, int TH, int TW>
__global__ __launch_bounds__(256) void ratio_oc3_kernel(
    const float* __restrict__ h, const float* __restrict__ wA4,
    const float* __restrict__ xn, float* __restrict__ ratio,
    const float* __restrict__ S, int H, int W)
{
    constexpr int NPX = 2;
    constexpr int HS = TH + 2, WSg = TW + 2;
    constexpr int WS = ((WSg + 3) / 4) * 4;
    constexpr int SPR = TW / NPX;
    constexpr int NCH = IC / ICB;
    constexpr int NIF = ICB * HS * WSg;
    constexpr int IREG = (NIF + 255) / 256;
    static_assert(TH * TW == 256 * NPX, "tile size");

    __shared__ float w_l[IC * 36];
    __shared__ float in_t[ICB * HS * WS];
    __shared__ float rS[HS * WSg];

    const int tid  = threadIdx.x;
    const int row  = tid / SPR;
    const int col0 = (tid & (SPR - 1)) * NPX;
    const int x0 = blockIdx.x * TW, y0 = blockIdx.y * TH;
    const int b  = blockIdx.z;
    const int HW = H * W;

    {
        const float4* wsrc = reinterpret_cast<const float4*>(wA4);
        float4* wdst = reinterpret_cast<float4*>(w_l);
        #pragma unroll
        for (int r = 0; r < (IC * 9 + 255) / 256; ++r) {
            const int i = tid + r * 256;
            if (i < IC * 9) wdst[i] = wsrc[i];
        }
    }
    for (int i = tid; i < HS * WSg; i += 256) {
        const int yy = y0 + i / WSg - 1, xx = x0 + i % WSg - 1;
        float sv = 0.f;
        if (yy >= 0 && yy < H && xx >= 0 && xx < W)
            sv = S[(size_t)b * HW + (size_t)yy * W + xx];
        rS[i] = 1.f / (sv + EPSV);
    }

    float pre[IREG];
    #pragma unroll
    for (int r = 0; r < IREG; ++r) {
        const int i = tid + r * 256;
        float v = 0.f;
        if (i < NIF) {
            const int ic = i / (HS * WSg), rr = (i % (HS * WSg)) / WSg, cc = i % WSg;
            const int yy = y0 + rr - 1, xx = x0 + cc - 1;
            if (yy >= 0 && yy < H && xx >= 0 && xx < W)
                v = h[((size_t)(b * IC + ic)) * HW + (size_t)yy * W + xx];
        }
        pre[r] = v;
    }
    __syncthreads();
    #pragma unroll
    for (int r = 0; r < IREG; ++r) {
        const int i = tid + r * 256;
        if (i < NIF) {
            const int ic = i / (HS * WSg), rr = (i % (HS * WSg)) / WSg, cc = i % WSg;
            in_t[ic * (HS * WS) + rr * WS + cc] = pre[r] * rS[rr * WSg + cc];
        }
    }
    __syncthreads();

    float acc0[NPX], acc1[NPX], acc2[NPX];
    #pragma unroll
    for (int p = 0; p < NPX; ++p) { acc0[p] = 0.f; acc1[p] = 0.f; acc2[p] = 0.f; }

    for (int c = 0; c < NCH; ++c) {
        if (c + 1 < NCH) {
            #pragma unroll
            for (int r = 0; r < IREG; ++r) {
                const int i = tid + r * 256;
                float v = 0.f;
                if (i < NIF) {
                    const int ic = i / (HS * WSg), rr = (i % (HS * WSg)) / WSg, cc = i % WSg;
                    const int yy = y0 + rr - 1, xx = x0 + cc - 1;
                    if (yy >= 0 && yy < H && xx >= 0 && xx < W)
                        v = h[((size_t)(b * IC + (c + 1) * ICB + ic)) * HW + (size_t)yy * W + xx];
                }
                pre[r] = v;
            }
        }
        for (int ic = 0; ic < ICB; ++ic) {
            const float* ib = in_t + ic * (HS * WS) + row * WS + col0;
            float win[3][4];
            #pragma unroll
            for (int dy = 0; dy < 3; ++dy) {
                const float2 a = *reinterpret_cast<const float2*>(ib + dy * WS);
                const float2 bb = *reinterpret_cast<const float2*>(ib + dy * WS + 2);
                win[dy][0] = a.x; win[dy][1] = a.y; win[dy][2] = bb.x; win[dy][3] = bb.y;
            }
            const float* wb = w_l + (c * ICB + ic) * 36;
            #pragma unroll
            for (int t = 0; t < 9; ++t) {
                const float4 wv = *reinterpret_cast<const float4*>(wb + t * 4);
                const int ky = t / 3, kx = t % 3;
                #pragma unroll
                for (int p = 0; p < NPX; ++p) {
                    const float v = win[ky][kx + p];
                    acc0[p] = fmaf(v, wv.x, acc0[p]);
                    acc1[p] = fmaf(v, wv.y, acc1[p]);
                    acc2[p] = fmaf(v, wv.z, acc2[p]);
                }
            }
        }
        __syncthreads();
        if (c + 1 < NCH) {
            #pragma unroll
            for (int r = 0; r < IREG; ++r) {
                const int i = tid + r * 256;
                if (i < NIF) {
                    const int ic = i / (HS * WSg), rr = (i % (HS * WSg)) / WSg, cc = i % WSg;
                    in_t[ic * (HS * WS) + rr * WS + cc] = pre[r] * rS[rr * WSg + cc];
                }
            }
        }
        __syncthreads();
    }

    const int gy = y0 + row, gx0 = x0 + col0;
    const size_t p0 = ((size_t)(b * 3)) * HW + (size_t)gy * W + gx0;
    float* accs[3] = {acc0, acc1, acc2};
    #pragma unroll
    for (int oc = 0; oc < 3; ++oc) {
        const size_t idx = p0 + (size_t)oc * HW;
        const float2 av = *reinterpret_cast<const float2*>(xn + idx);
        float2 ov;
        ov.x = av.x / (accs[oc][0] + EPSV);
        ov.y = av.y / (accs[oc][1] + EPSV);
        *reinterpret_cast<float2*>(ratio + idx) = ov;
    }
}

// ---------------------------------------------------------------------------
// Block-0 update conv (3 -> 64), fp32 register-tiled — from R3, unchanged.
// ---------------------------------------------------------------------------
template<int IC, int OC, int TH, int TW, int PXT, int NPX, int NOC, int ICB,
         bool NORM_IN, bool UPDATE>
__global__ __launch_bounds__(256) void conv3v3_kernel(
    const float* __restrict__ in, const float* __restrict__ wgt,
    const float* __restrict__ aux, float* __restrict__ out,
    const float* __restrict__ Sin, float* __restrict__ Sout,
    int H, int W)
{
    constexpr int OCG = 256 / PXT;
    constexpr int TPX = TH * TW;
    constexpr int SPR = TW / NPX;
    constexpr int HS  = TH + 2;
    constexpr int WSg = TW + 2;
    constexpr int WS  = ((WSg + 3) / 4) * 4;
    constexpr int NCH = IC / ICB;
    constexpr int NIF = ICB * HS * WSg;
    constexpr int IREG = (NIF + 255) / 256;
    constexpr int NWF = ICB * 9 * OC;
    constexpr int NW4 = NWF / 4;
    constexpr int WREG = (NW4 + 255) / 256;
    static_assert(TPX == PXT * NPX, "tile mismatch");
    static_assert(OCG * NOC >= OC, "oc coverage");
    static_assert(NPX == 4 && NOC % 4 == 0 && NWF % 4 == 0 && IC % ICB == 0, "cfg");

    __shared__ float in_t[ICB * HS * WS];
    __shared__ float w_t[NWF];
    __shared__ float rS[NORM_IN ? HS * WSg : 1];
    __shared__ float red[UPDATE ? OCG * TPX : 1];

    const int tid  = threadIdx.x;
    const int pxs  = tid % PXT;
    const int ocg  = tid / PXT;
    const int row  = pxs / SPR;
    const int col0 = (pxs % SPR) * NPX;
    const int x0 = blockIdx.x * TW, y0 = blockIdx.y * TH;
    const int b  = blockIdx.z;
    const int HW = H * W;

    if constexpr (NORM_IN) {
        for (int i = tid; i < HS * WSg; i += 256) {
            const int yy = y0 + i / WSg - 1, xx = x0 + i % WSg - 1;
            float sv = 0.f;
            if (yy >= 0 && yy < H && xx >= 0 && xx < W)
                sv = Sin[(size_t)b * HW + (size_t)yy * W + xx];
            rS[i] = 1.f / (sv + EPSV);
        }
    }

    float ipre[IREG];
    float4 wpre[WREG];
    const float4* wsrc4 = reinterpret_cast<const float4*>(wgt);

    #pragma unroll
    for (int r = 0; r < IREG; ++r) {
        const int i = tid + r * 256;
        float v = 0.f;
        if (i < NIF) {
            const int ic = i / (HS * WSg), rr = (i % (HS * WSg)) / WSg, cc = i % WSg;
            const int yy = y0 + rr - 1, xx = x0 + cc - 1;
            if (yy >= 0 && yy < H && xx >= 0 && xx < W)
                v = in[((size_t)(b * IC + ic)) * HW + (size_t)yy * W + xx];
        }
        ipre[r] = v;
    }
    #pragma unroll
    for (int r = 0; r < WREG; ++r) {
        const int i = tid + r * 256;
        if (i < NW4) wpre[r] = wsrc4[i];
    }
    __syncthreads();
    #pragma unroll
    for (int r = 0; r < IREG; ++r) {
        const int i = tid + r * 256;
        if (i < NIF) {
            const int ic = i / (HS * WSg), rr = (i % (HS * WSg)) / WSg, cc = i % WSg;
            float v = ipre[r];
            if constexpr (NORM_IN) v *= rS[rr * WSg + cc];
            in_t[ic * (HS * WS) + rr * WS + cc] = v;
        }
    }
    {
        float4* wdst = reinterpret_cast<float4*>(w_t);
        #pragma unroll
        for (int r = 0; r < WREG; ++r) {
            const int i = tid + r * 256;
            if (i < NW4) wdst[i] = wpre[r];
        }
    }
    __syncthreads();

    float acc[NOC][NPX];
    #pragma unroll
    for (int j = 0; j < NOC; ++j)
        #pragma unroll
        for (int p = 0; p < NPX; ++p) acc[j][p] = 0.f;

    for (int c = 0; c < NCH; ++c) {
        if (c + 1 < NCH) {
            #pragma unroll
            for (int r = 0; r < IREG; ++r) {
                const int i = tid + r * 256;
                float v = 0.f;
                if (i < NIF) {
                    const int ic = i / (HS * WSg), rr = (i % (HS * WSg)) / WSg, cc = i % WSg;
                    const int yy = y0 + rr - 1, xx = x0 + cc - 1;
                    if (yy >= 0 && yy < H && xx >= 0 && xx < W)
                        v = in[((size_t)(b * IC + (c + 1) * ICB + ic)) * HW + (size_t)yy * W + xx];
                }
                ipre[r] = v;
            }
            #pragma unroll
            for (int r = 0; r < WREG; ++r) {
                const int i = tid + r * 256;
                if (i < NW4) wpre[r] = wsrc4[(size_t)(c + 1) * NW4 + i];
            }
        }
        for (int ic = 0; ic < ICB; ++ic) {
            const float* wbase = w_t + ic * 9 * OC;
            const float* ibase = in_t + ic * (HS * WS) + row * WS + col0;

            float win[3][6];
            #pragma unroll
            for (int dy = 0; dy < 3; ++dy) {
                const float* rp = ibase + dy * WS;
                const float4 a = *reinterpret_cast<const float4*>(rp);
                const float2 cxy = *reinterpret_cast<const float2*>(rp + 4);
                win[dy][0] = a.x; win[dy][1] = a.y; win[dy][2] = a.z; win[dy][3] = a.w;
                win[dy][4] = cxy.x; win[dy][5] = cxy.y;
            }
            #pragma unroll
            for (int t = 0; t < 9; ++t) {
                const int ky = t / 3, kx = t % 3;
                #pragma unroll
                for (int j4 = 0; j4 < NOC / 4; ++j4) {
                    const float4 wv = *reinterpret_cast<const float4*>(
                        wbase + t * OC + ocg * NOC + j4 * 4);
                    #pragma unroll
                    for (int p = 0; p < NPX; ++p) {
                        const float v = win[ky][kx + p];
                        acc[j4 * 4 + 0][p] = fmaf(v, wv.x, acc[j4 * 4 + 0][p]);
                        acc[j4 * 4 + 1][p] = fmaf(v, wv.y, acc[j4 * 4 + 1][p]);
                        acc[j4 * 4 + 2][p] = fmaf(v, wv.z, acc[j4 * 4 + 2][p]);
                        acc[j4 * 4 + 3][p] = fmaf(v, wv.w, acc[j4 * 4 + 3][p]);
                    }
                }
            }
        }
        __syncthreads();
        if (c + 1 < NCH) {
            #pragma unroll
            for (int r = 0; r < IREG; ++r) {
                const int i = tid + r * 256;
                if (i < NIF) {
                    const int ic = i / (HS * WSg), rr = (i % (HS * WSg)) / WSg, cc = i % WSg;
                    float v = ipre[r];
                    if constexpr (NORM_IN) v *= rS[rr * WSg + cc];
                    in_t[ic * (HS * WS) + rr * WS + cc] = v;
                }
            }
            float4* wdst = reinterpret_cast<float4*>(w_t);
            #pragma unroll
            for (int r = 0; r < WREG; ++r) {
                const int i = tid + r * 256;
                if (i < NW4) wdst[i] = wpre[r];
            }
            __syncthreads();
        }
    }

    const int gy = y0 + row, gx0 = x0 + col0;

    if constexpr (!UPDATE) {
        #pragma unroll
        for (int j = 0; j < NOC; ++j) {
            const int oc = ocg * NOC + j;
            if constexpr (OCG * NOC > OC) { if (oc >= OC) continue; }
            const size_t idx = ((size_t)(b * OC + oc)) * HW + (size_t)gy * W + gx0;
            const float4 av = *reinterpret_cast<const float4*>(aux + idx);
            float4 ov;
            ov.x = av.x / (acc[j][0] + EPSV);
            ov.y = av.y / (acc[j][1] + EPSV);
            ov.z = av.z / (acc[j][2] + EPSV);
            ov.w = av.w / (acc[j][3] + EPSV);
            *reinterpret_cast<float4*>(out + idx) = ov;
        }
    } else {
        float psum[NPX];
        #pragma unroll
        for (int p = 0; p < NPX; ++p) psum[p] = 0.f;
        #pragma unroll
        for (int j = 0; j < NOC; ++j) {
            const int oc = ocg * NOC + j;
            if constexpr (OCG * NOC > OC) { if (oc >= OC) continue; }
            const size_t idx = ((size_t)(b * OC + oc)) * HW + (size_t)gy * W + gx0;
            float4 hv = *reinterpret_cast<const float4*>(out + idx);
            hv.x *= acc[j][0]; hv.y *= acc[j][1]; hv.z *= acc[j][2]; hv.w *= acc[j][3];
            psum[0] += hv.x; psum[1] += hv.y; psum[2] += hv.z; psum[3] += hv.w;
            *reinterpret_cast<float4*>(out + idx) = hv;
        }
        const int pix0 = row * TW + col0;
        #pragma unroll
        for (int p = 0; p < NPX; ++p) red[ocg * TPX + pix0 + p] = psum[p];
        __syncthreads();
        if (tid < TPX) {
            float s = 0.f;
            #pragma unroll
            for (int g = 0; g < OCG; ++g) s += red[g * TPX + tid];
            const int py = tid / TW, pxx = tid % TW;
            Sout[(size_t)b * HW + (size_t)(y0 + py) * W + (x0 + pxx)] = s;
        }
    }
}

// ---------------------------------------------------------------------------
// postY (MFMA): Y[pix,oc] = relu(W1.(h/S) + bias) as f16, + per-WG BN partials.
//   WG = 64 contiguous pixels x ALL oc. A staged f16 in LDS; B = w1h [oc][c].
//   part[(wgid*C+oc)*2 + {0,1}] = (sum y, sum y^2) over the 64 pixels.
// ---------------------------------------------------------------------------
template<int C>
__global__ __launch_bounds__(256) void posty_kernel(
    const float* __restrict__ h, const float* __restrict__ S,
    const _Float16* __restrict__ w1h, const float* __restrict__ bias,
    _Float16* __restrict__ Y, float* __restrict__ part, int HW)
{
    constexpr int NF = C / 16;
    constexpr int CP = C + 8;

    __shared__ _Float16 a_t[64 * CP];
    __shared__ float rs_t[64];
    __shared__ float sred1[4 * C];
    __shared__ float sred2[4 * C];

    const int tid  = threadIdx.x;
    const int lane = tid & 63, wave = tid >> 6;
    const int kq = lane >> 4, l15 = lane & 15;
    const int p0 = blockIdx.x * 64;
    const int b  = blockIdx.y;
    const int wgid = b * gridDim.x + blockIdx.x;

    if (tid < 64)
        rs_t[tid] = 1.f / (S[(size_t)b * HW + p0 + tid] + EPSV);
    __syncthreads();

    for (int i = tid; i < (C / 2) * 64; i += 256) {
        const int k2 = i >> 6, sp = i & 63;
        const size_t ba = ((size_t)(b * C + 2 * k2)) * HW + p0 + sp;
        const float f = rs_t[sp];
        *reinterpret_cast<unsigned*>(&a_t[sp * CP + 2 * k2]) =
            pack2f16(h[ba] * f, h[ba + HW] * f);
    }
    __syncthreads();

    f32x4 acc[NF];
    #pragma unroll
    for (int nf = 0; nf < NF; ++nf) acc[nf] = (f32x4){0.f, 0.f, 0.f, 0.f};

    #pragma unroll
    for (int kc = 0; kc < C / 32; ++kc) {
        const f16x8 afr = *reinterpret_cast<const f16x8*>(
            &a_t[(wave * 16 + l15) * CP + kc * 32 + kq * 8]);
        #pragma unroll
        for (int nf = 0; nf < NF; ++nf) {
            const f16x8 bfr = *reinterpret_cast<const f16x8*>(
                w1h + ((size_t)(nf * 16 + l15)) * C + kc * 32 + kq * 8);
            acc[nf] = __builtin_amdgcn_mfma_f32_16x16x32_f16(afr, bfr, acc[nf], 0, 0, 0);
        }
    }

    // epilogue: lane -> pixels [wave*16+kq*4, +4), oc = nf*16+l15
    const int pl = wave * 16 + kq * 4;
    #pragma unroll
    for (int nf = 0; nf < NF; ++nf) {
        const int oc = nf * 16 + l15;
        const float bv = bias[oc];
        float y0v = fmaxf(acc[nf][0] + bv, 0.f);
        float y1v = fmaxf(acc[nf][1] + bv, 0.f);
        float y2v = fmaxf(acc[nf][2] + bv, 0.f);
        float y3v = fmaxf(acc[nf][3] + bv, 0.f);
        f16x4 yv = { (_Float16)y0v, (_Float16)y1v, (_Float16)y2v, (_Float16)y3v };
        *reinterpret_cast<f16x4*>(Y + ((size_t)(b * C + oc)) * HW + p0 + pl) = yv;
        float s1 = y0v + y1v + y2v + y3v;
        float s2 = y0v * y0v + y1v * y1v + y2v * y2v + y3v * y3v;
        #pragma unroll
        for (int mm = 16; mm < 64; mm <<= 1) {
            s1 += __shfl_xor(s1, mm);
            s2 += __shfl_xor(s2, mm);
        }
        if (kq == 0) {
            sred1[wave * C + oc] = s1;
            sred2[wave * C + oc] = s2;
        }
    }
    __syncthreads();
    for (int oc = tid; oc < C; oc += 256) {
        const float s1 = sred1[oc] + sred1[C + oc] + sred1[2 * C + oc] + sred1[3 * C + oc];
        const float s2 = sred2[oc] + sred2[C + oc] + sred2[2 * C + oc] + sred2[3 * C + oc];
        part[((size_t)wgid * C + oc) * 2 + 0] = s1;
        part[((size_t)wgid * C + oc) * 2 + 1] = s2;
    }
}

// Reduce partials -> per-channel (scale, shift) for BN affine.
template<int C>
__global__ __launch_bounds__(256) void stats_kernel(const float* __restrict__ part, int nwg, float invM,
                                                    const float* __restrict__ gamma,
                                                    const float* __restrict__ beta,
                                                    float* __restrict__ stats)
{
    const int oc = blockIdx.x;
    const int tid = threadIdx.x;
    float s1 = 0.f, s2 = 0.f;
    for (int w = tid; w < nwg; w += 256) {
        s1 += part[((size_t)w * C + oc) * 2 + 0];
        s2 += part[((size_t)w * C + oc) * 2 + 1];
    }
    __shared__ float r1[4], r2[4];
    #pragma unroll
    for (int m = 32; m; m >>= 1) { s1 += __shfl_xor(s1, m, 64); s2 += __shfl_xor(s2, m, 64); }
    if ((tid & 63) == 0) { r1[tid >> 6] = s1; r2[tid >> 6] = s2; }
    __syncthreads();
    if (tid == 0) {
        s1 = r1[0] + r1[1] + r1[2] + r1[3];
        s2 = r2[0] + r2[1] + r2[2] + r2[3];
        const float mean = s1 * invM;
        const float var  = s2 * invM - mean * mean;
        const float rstd = rsqrtf(var + BNEPS);
        const float scale = gamma[oc] * rstd;
        stats[oc]     = scale;
        stats[C + oc] = beta[oc] - mean * scale;
    }
}

// bnpool: out[b][c][y][x] = pool2x2(Y)[...] * scale[c] + shift[c]  (pool⊥affine)
__global__ __launch_bounds__(256) void bnpool_kernel(
    const _Float16* __restrict__ Y, const float* __restrict__ stats,
    float* __restrict__ out, int C, int H, int W, int ntot)
{
    const int idx = blockIdx.x * 256 + threadIdx.x;
    if (idx >= ntot) return;
    const int Wo = W >> 1;
    const int x = idx % Wo;
    int t = idx / Wo;
    const int y = t % (H >> 1);
    t /= (H >> 1);
    const int c = t % C;
    const size_t base = ((size_t)t * H + 2 * y) * W + 2 * x;
    const float v = ((float)Y[base] + (float)Y[base + 1] +
                     (float)Y[base + W] + (float)Y[base + W + 1]) * 0.25f;
    out[idx] = v * stats[c] + stats[C + c];
}

// ---------------------------------------------------------------------------
// Drivers
// ---------------------------------------------------------------------------
template<int C>
static void post_phase_t(const float* h, const float* S, const float* w1, const float* bias,
                         const float* gamma, const float* beta, float* pout,
                         float* part, float* stats, _Float16* w1h, _Float16* Y,
                         int H, int W, hipStream_t stream)
{
    const int B = 16, HW = H * W;
    prep_w1h_kernel<<<(C * C + 255) / 256, 256, 0, stream>>>(w1, w1h, C * C);
    dim3 pg(HW / 64, B);
    posty_kernel<C><<<pg, 256, 0, stream>>>(h, S, w1h, bias, Y, part, HW);
    const int nwg = pg.x * pg.y;
    stats_kernel<C><<<C, 256, 0, stream>>>(part, nwg, 1.0f / (float)(B * HW), gamma, beta, stats);
    const int ntot = B * C * (HW / 4);
    bnpool_kernel<<<(ntot + 255) / 256, 256, 0, stream>>>(Y, stats, pout, C, H, W, ntot);
}

extern "C" void kernel_launch(void* const* d_in, const int* in_sizes, int n_in,
                              void* d_out, int out_size, void* d_ws, size_t ws_size,
                              hipStream_t stream)
{
    const float* x = (const float*)d_in[0];
    float* ws    = (float*)d_ws;
    float* h     = ws;                    // 16,777,216
    float* xn    = h     + 16777216;      //  4,194,304
    float* ratio = xn    + 4194304;       //  4,194,304
    float* out0  = ratio + 4194304;       //  4,194,304
    float* out1  = out0  + 4194304;       //  2,097,152
    float* S     = out1  + 2097152;       //    262,144
    float* wA    = S     + 262144;        //      4,096 (block0 fp32)
    float* wB    = wA    + 4096;          //      4,096 (block0 fp32)
    float* part  = wB    + 4096;          //  1,048,576
    float* stats = part  + 1048576;       //        512
    _Float16* wAh = (_Float16*)(stats + 512);       // 294,912 f16
    _Float16* wBh = wAh + 294912;                   // 294,912 f16
    _Float16* w1h = wBh + 294912;                   //  65,536 f16
    // Y overlays the (dead-at-post-time) xn+ratio region: 8,388,608 floats.
    _Float16* Y   = (_Float16*)xn;

    const int B = 16;

    // ---------------- Block 0: Cin=3, Cout=64, 128x128 ----------------
    {
        const int H = 128, W = 128, HW = H * W;
        prep_w_kernel<3, 64, 4><<<64, 256, 0, stream>>>((const float*)d_in[1], wA, wB);
        const int npx = B * HW;
        xn_kernel<3><<<(npx + 255) / 256, 256, 0, stream>>>(x, xn, npx, HW);
        const int nh = B * 64 * HW;
        init_h_kernel<<<(nh + 255) / 256, 256, 0, stream>>>(h, S, nh, npx, 64.f);
        for (int it = 0; it < 5; ++it) {
            ratio_oc3_kernel<64, 8, 32, 16>
                <<<dim3(W / 16, H / 32, B), 256, 0, stream>>>(h, wA, xn, ratio, S, H, W);
            conv3v3_kernel<3, 64, 16, 16, 64, 4, 16, 3, false, true>
                <<<dim3(W / 16, H / 16, B), 256, 0, stream>>>(ratio, wB, nullptr, h, nullptr, S, H, W);
        }
        post_phase_t<64>(h, S, (const float*)d_in[2], (const float*)d_in[3],
                         (const float*)d_in[4], (const float*)d_in[5],
                         out0, part, stats, w1h, Y, H, W, stream);
    }

    // ---------------- Block 1: Cin=64, Cout=128, 64x64 (MFMA) ----------------
    {
        const int H = 64, W = 64, HW = H * W;
        prep_w_f16_kernel<64, 128><<<128, 256, 0, stream>>>((const float*)d_in[6], wAh, wBh);
        const int npx = B * HW;
        xn_kernel<64><<<(npx + 255) / 256, 256, 0, stream>>>(out0, xn, npx, HW);
        const int nh = B * 128 * HW;
        init_h_kernel<<<(nh + 255) / 256, 256, 0, stream>>>(h, S, nh, npx, 128.f);
        for (int it = 0; it < 5; ++it) {
            mfconv_kernel<128, 64, 4, 16, 1, true, false>
                <<<dim3(4, 16, B), 256, 0, stream>>>(h, wAh, xn, ratio, S, nullptr, H, W, 0);
            mfconv_kernel<64, 128, 4, 16, 1, false, true>
                <<<dim3(4, 16, B), 256, 0, stream>>>(ratio, wBh, nullptr, h, nullptr, S, H, W, 0);
        }
        post_phase_t<128>(h, S, (const float*)d_in[7], (const float*)d_in[8],
                          (const float*)d_in[9], (const float*)d_in[10],
                          out1, part, stats, w1h, Y, H, W, stream);
    }

    // ---------------- Block 2: Cin=128, Cout=256, 32x32 (MFMA) ----------------
    {
        const int H = 32, W = 32, HW = H * W;
        prep_w_f16_kernel<128, 256><<<256, 256, 0, stream>>>((const float*)d_in[11], wAh, wBh);
        const int npx = B * HW;
        xn_kernel<128><<<(npx + 255) / 256, 256, 0, stream>>>(out1, xn, npx, HW);
        const int nh = B * 256 * HW;
        init_h_kernel<<<(nh + 255) / 256, 256, 0, stream>>>(h, S, nh, npx, 256.f);
        for (int it = 0; it < 5; ++it) {
            mfconv_kernel<256, 128, 8, 8, 2, true, false>
                <<<dim3(8, 4, B), 256, 0, stream>>>(h, wAh, xn, ratio, S, nullptr, H, W, 0);
            mfconv_kernel<128, 256, 8, 8, 2, false, true>
                <<<dim3(8, 4, B), 256, 0, stream>>>(ratio, wBh, nullptr, h, nullptr, part, H, W, npx);
            combine_S_kernel<<<(npx + 255) / 256, 256, 0, stream>>>(part, S, npx);
        }
        post_phase_t<256>(h, S, (const float*)d_in[12], (const float*)d_in[13],
                          (const float*)d_in[14], (const float*)d_in[15],
                          (float*)d_out, part, stats, w1h, Y, H, W, stream);
    }
}

// Round 6
// 2045.188 us; speedup vs baseline: 3.7487x; 1.2951x over previous
//
#include <hip/hip_runtime.h>

#define EPSV  1e-20f
#define BNEPS 1e-5f

typedef _Float16 f16x8 __attribute__((ext_vector_type(8)));
typedef _Float16 f16x4 __attribute__((ext_vector_type(4)));
typedef float    f32x4 __attribute__((ext_vector_type(4)));

__device__ inline unsigned pack2f16(float a, float b) {
    unsigned short ua = __builtin_bit_cast(unsigned short, (_Float16)a);
    unsigned short ub = __builtin_bit_cast(unsigned short, (_Float16)b);
    return ((unsigned)ub << 16) | ua;
}

// ---------------------------------------------------------------------------
// Weight prep (blocks 1/2): wn = |w|/(sum+eps), f16 GEMM layouts
//   wBh[tap][co][ci]  (update conv: n=co, k=ci)
//   wAh[tapf][ci][co] (ratio conv:  n=ci, k=co)
// ---------------------------------------------------------------------------
template<int CIN, int COUT>
__global__ __launch_bounds__(256) void prep_w_f16_kernel(const float* __restrict__ w,
                                                         _Float16* __restrict__ wAh,
                                                         _Float16* __restrict__ wBh)
{
    const int co  = blockIdx.x;
    const int tid = threadIdx.x;
    const int N   = CIN * 9;
    const float* wrow = w + (size_t)co * N;

    float s = 0.f;
    for (int i = tid; i < N; i += 256) s += fabsf(wrow[i]);
    __shared__ float red[4];
    #pragma unroll
    for (int m = 32; m; m >>= 1) s += __shfl_xor(s, m, 64);
    if ((tid & 63) == 0) red[tid >> 6] = s;
    __syncthreads();
    s = red[0] + red[1] + red[2] + red[3];
    const float rn = 1.f / (s + EPSV);

    for (int i = tid; i < N; i += 256) {
        const int ci = i / 9, tap = i % 9;
        const int ky = tap / 3, kx = tap % 3;
        const float v = fabsf(wrow[i]) * rn;
        const int tf = (2 - ky) * 3 + (2 - kx);
        wBh[((size_t)tap * COUT + co) * CIN + ci] = (_Float16)v;
        wAh[((size_t)tf * CIN + ci) * COUT + co] = (_Float16)v;
    }
}

// Block0 weight prep: wB0h[co][tap*4+ci] (K=36 pad 64), wA0h[tapf][ci(16p)][co(64)]
__global__ __launch_bounds__(256) void zero_f16_kernel(_Float16* __restrict__ a, int n)
{
    const int i = blockIdx.x * 256 + threadIdx.x;
    if (i < n) a[i] = (_Float16)0.f;
}

__global__ __launch_bounds__(64) void prep_w0_kernel(const float* __restrict__ w,
                                                     _Float16* __restrict__ wA0h,
                                                     _Float16* __restrict__ wB0h)
{
    const int co = blockIdx.x, tid = threadIdx.x;  // 64 threads, 1 wave
    float s = (tid < 27) ? fabsf(w[co * 27 + tid]) : 0.f;
    #pragma unroll
    for (int m = 32; m; m >>= 1) s += __shfl_xor(s, m, 64);
    const float rn = 1.f / (s + EPSV);
    if (tid < 27) {
        const int ci = tid / 9, tap = tid % 9, ky = tap / 3, kx = tap % 3;
        const float v = fabsf(w[co * 27 + tid]) * rn;
        wB0h[co * 64 + tap * 4 + ci] = (_Float16)v;
        wA0h[(((2 - ky) * 3 + (2 - kx)) * 16 + ci) * 64 + co] = (_Float16)v;
    }
}

__global__ __launch_bounds__(256) void prep_w1h_kernel(const float* __restrict__ w1,
                                                       _Float16* __restrict__ w1h, int n)
{
    const int i = blockIdx.x * 256 + threadIdx.x;
    if (i < n) w1h[i] = (_Float16)w1[i];
}

// ---------------------------------------------------------------------------
// xn prep.  Block0: x NCHW fp32 -> xn [pix][4] f16 (ch3=0).
//           Blocks1/2: prev out NHWC f16 -> relu/L1-normalize per pixel.
// ---------------------------------------------------------------------------
__global__ __launch_bounds__(256) void xn0_kernel(const float* __restrict__ x,
                                                  _Float16* __restrict__ xn4,
                                                  int npx, int HW)
{
    const int p = blockIdx.x * 256 + threadIdx.x;
    if (p >= npx) return;
    const int b = p / HW, r = p % HW;
    const float* ip = x + (size_t)b * 3 * HW + r;
    const float v0 = fmaxf(ip[0], 0.f), v1 = fmaxf(ip[HW], 0.f), v2 = fmaxf(ip[2 * HW], 0.f);
    const float rs = 1.f / (v0 + v1 + v2 + EPSV);
    unsigned* d = (unsigned*)(xn4 + (size_t)p * 4);
    d[0] = pack2f16(v0 * rs, v1 * rs);
    d[1] = pack2f16(v2 * rs, 0.f);
}

template<int C>
__global__ __launch_bounds__(256) void xn12_kernel(const _Float16* __restrict__ prev,
                                                   _Float16* __restrict__ xn, int npx)
{
    const int p = blockIdx.x * 256 + threadIdx.x;
    if (p >= npx) return;
    const _Float16* ip = prev + (size_t)p * C;
    _Float16* op = xn + (size_t)p * C;
    f16x8 buf[C / 8];
    float s = 0.f;
    #pragma unroll
    for (int g = 0; g < C / 8; ++g) {
        buf[g] = *(const f16x8*)(ip + g * 8);
        #pragma unroll
        for (int j = 0; j < 8; ++j) {
            float v = fmaxf((float)buf[g][j], 0.f);
            s += v;
            buf[g][j] = (_Float16)v;
        }
    }
    const float rs = 1.f / (s + EPSV);
    #pragma unroll
    for (int g = 0; g < C / 8; ++g) {
        f16x8 o;
        #pragma unroll
        for (int j = 0; j < 8; ++j) o[j] = (_Float16)((float)buf[g][j] * rs);
        *(f16x8*)(op + g * 8) = o;
    }
}

__global__ __launch_bounds__(256) void init_h_kernel(float* __restrict__ h, float* __restrict__ S,
                                                     int nh, int ns, float cval)
{
    const int i = blockIdx.x * 256 + threadIdx.x;
    if (i < nh) h[i] = 1.f;
    if (i < ns) S[i] = cval;
}

__global__ __launch_bounds__(256) void combine_S_kernel(const float* __restrict__ sp,
                                                        float* __restrict__ S, int npx)
{
    const int i = blockIdx.x * 256 + threadIdx.x;
    if (i < npx) S[i] = sp[i] + sp[npx + i];
}

// ---------------------------------------------------------------------------
// NHWC MFMA implicit-GEMM 3x3 'same' conv.
//   64-pixel tile (TH x TW), 4 waves; wave owns one M-frag, WG owns OCWG ocs.
//   IN_F16: input f16 NHWC (update conv reads ratio; direct LDS copy).
//   else fp32 NHWC h, NORM_IN scales by 1/(Sin+eps) while converting to f16.
//   !UPDATE: out f16 = aux/(acc+eps), channel stride OST, only oc<NW written.
//   UPDATE : out fp32 h RMW (*= acc), Sout per-pixel channel sums via shfl.
// Weights: wgt[tap][n(OCg)][k(ICg)] f16.
// ---------------------------------------------------------------------------
template<int ICg, int OCg, int TH, int TW, int NSPLIT, int OST, int NW,
         bool NORM_IN, bool UPDATE, bool IN_F16>
__global__ __launch_bounds__(256) void mfconv_nhwc(
    const void* __restrict__ in_, const _Float16* __restrict__ wgt,
    const _Float16* __restrict__ aux, void* __restrict__ out_,
    const float* __restrict__ Sin, float* __restrict__ Sout,
    int H, int W, int sstride)
{
    constexpr int OCWG = OCg / NSPLIT;
    constexpr int NF = OCWG / 16;
    constexpr int HS = TH + 2, WSp = TW + 2, NSP = HS * WSp;
    constexpr int ICB = 32, ICP = ICB + 8, NCH = ICg / ICB;
    constexpr int LS = (NSPLIT == 2) ? 1 : 0;
    static_assert(TH * TW == 64 && OCWG % 16 == 0 && ICg % 32 == 0, "cfg");

    __shared__ _Float16 in_t[NSP * ICP];
    __shared__ float rS[NORM_IN ? NSP : 1];

    const int tid = threadIdx.x;
    const int lane = tid & 63, wave = tid >> 6;
    const int kq = lane >> 4, l15 = lane & 15;
    const int split = blockIdx.x & (NSPLIT - 1);
    const int tx = blockIdx.x >> LS;
    const int x0 = tx * TW, y0 = blockIdx.y * TH, b = blockIdx.z;
    const int HW = H * W;
    const int oc0 = split * OCWG;

    if constexpr (NORM_IN) {
        for (int i = tid; i < NSP; i += 256) {
            const int yy = y0 + i / WSp - 1, xx = x0 + i % WSp - 1;
            float sv = 0.f;
            if (yy >= 0 && yy < H && xx >= 0 && xx < W)
                sv = Sin[(size_t)b * HW + (size_t)yy * W + xx];
            rS[i] = 1.f / (sv + EPSV);
        }
    }

    const int m = wave * 16 + l15;
    const int pyl = m / TW, pxl = m % TW;

    f32x4 acc[NF];
    #pragma unroll
    for (int nf = 0; nf < NF; ++nf) acc[nf] = (f32x4){0.f, 0.f, 0.f, 0.f};

    for (int icc = 0; icc < NCH; ++icc) {
        if (icc > 0 || NORM_IN) __syncthreads();
        const int ic0 = icc * ICB;
        for (int i = tid; i < NSP * 4; i += 256) {
            const int sp = i >> 2, seg = i & 3;
            const int yy = y0 + sp / WSp - 1, xx = x0 + sp % WSp - 1;
            const bool ok = (yy >= 0 && yy < H && xx >= 0 && xx < W);
            if constexpr (IN_F16) {
                f16x8 v = {0, 0, 0, 0, 0, 0, 0, 0};
                if (ok)
                    v = *(const f16x8*)((const _Float16*)in_ +
                        ((size_t)b * HW + (size_t)yy * W + xx) * ICg + ic0 + seg * 8);
                *(f16x8*)&in_t[sp * ICP + seg * 8] = v;
            } else {
                unsigned u0 = 0, u1 = 0, u2 = 0, u3 = 0;
                if (ok) {
                    const float* src = (const float*)in_ +
                        ((size_t)b * HW + (size_t)yy * W + xx) * ICg + ic0 + seg * 8;
                    const float4 a = *(const float4*)src;
                    const float4 c = *(const float4*)(src + 4);
                    float f = 1.f;
                    if constexpr (NORM_IN) f = rS[sp];
                    u0 = pack2f16(a.x * f, a.y * f);
                    u1 = pack2f16(a.z * f, a.w * f);
                    u2 = pack2f16(c.x * f, c.y * f);
                    u3 = pack2f16(c.z * f, c.w * f);
                }
                unsigned* d = (unsigned*)&in_t[sp * ICP + seg * 8];
                d[0] = u0; d[1] = u1; d[2] = u2; d[3] = u3;
            }
        }
        __syncthreads();

        #pragma unroll
        for (int tap = 0; tap < 9; ++tap) {
            const int dy = tap / 3, dx = tap % 3;
            f16x8 bfr[NF];
            #pragma unroll
            for (int nf = 0; nf < NF; ++nf) {
                const int oc = oc0 + nf * 16 + l15;
                bfr[nf] = *(const f16x8*)(
                    wgt + ((size_t)tap * OCg + oc) * ICg + ic0 + kq * 8);
            }
            const int sp = (pyl + dy) * WSp + pxl + dx;
            const f16x8 afr = *(const f16x8*)&in_t[sp * ICP + kq * 8];
            #pragma unroll
            for (int nf = 0; nf < NF; ++nf)
                acc[nf] = __builtin_amdgcn_mfma_f32_16x16x32_f16(afr, bfr[nf], acc[nf], 0, 0, 0);
        }
    }

    // epilogue: lane holds pixels (pl..pl+3) x oc; NHWC coalesced across l15.
    const int pl = wave * 16 + kq * 4;
    const int py0 = pl / TW, px0 = pl % TW;
    const size_t pixbase = (size_t)b * HW + (size_t)(y0 + py0) * W + x0 + px0;

    if constexpr (!UPDATE) {
        _Float16* outh = (_Float16*)out_;
        #pragma unroll
        for (int nf = 0; nf < NF; ++nf) {
            const int oc = oc0 + nf * 16 + l15;
            if (oc < NW) {
                #pragma unroll
                for (int r = 0; r < 4; ++r) {
                    const size_t idx = (pixbase + r) * OST + oc;
                    const float av = (float)aux[idx];
                    outh[idx] = (_Float16)(av / (acc[nf][r] + EPSV));
                }
            }
        }
    } else {
        float* outf = (float*)out_;
        float s[4] = {0.f, 0.f, 0.f, 0.f};
        #pragma unroll
        for (int nf = 0; nf < NF; ++nf) {
            const int oc = oc0 + nf * 16 + l15;
            #pragma unroll
            for (int r = 0; r < 4; ++r) {
                const size_t idx = (pixbase + r) * OST + oc;
                const float hv = outf[idx] * acc[nf][r];
                outf[idx] = hv;
                s[r] += hv;
            }
        }
        #pragma unroll
        for (int mm = 1; mm < 16; mm <<= 1) {
            #pragma unroll
            for (int r = 0; r < 4; ++r) s[r] += __shfl_xor(s[r], mm);
        }
        if (l15 == 0) {
            float* sp_ = Sout + (size_t)split * sstride + pixbase;
            sp_[0] = s[0]; sp_[1] = s[1]; sp_[2] = s[2]; sp_[3] = s[3];
        }
    }
}

// ---------------------------------------------------------------------------
// Block0 update conv (3 -> 64) via im2col MFMA: K = tap*4+ci (36 used, 64 pad).
// ---------------------------------------------------------------------------
__global__ __launch_bounds__(256) void mf0u_kernel(
    const _Float16* __restrict__ ratio4, const _Float16* __restrict__ wB0h,
    float* __restrict__ h, float* __restrict__ Sout, int H, int W)
{
    constexpr int TW = 16;
    __shared__ _Float16 a_t[64 * 72];

    const int tid = threadIdx.x;
    const int lane = tid & 63, wave = tid >> 6;
    const int kq = lane >> 4, l15 = lane & 15;
    const int x0 = blockIdx.x * TW, y0 = blockIdx.y * 4, b = blockIdx.z;
    const int HW = H * W;

    for (int i = tid; i < 64 * 72 / 2; i += 256) ((unsigned*)a_t)[i] = 0;
    __syncthreads();
    for (int i = tid; i < 576; i += 256) {
        const int px = i / 9, tap = i % 9;
        const int py = px / TW, pxx = px % TW;
        const int yy = y0 + py + tap / 3 - 1, xx = x0 + pxx + tap % 3 - 1;
        if (yy >= 0 && yy < H && xx >= 0 && xx < W)
            *(f16x4*)&a_t[px * 72 + tap * 4] =
                *(const f16x4*)(ratio4 + ((size_t)b * HW + (size_t)yy * W + xx) * 4);
    }
    __syncthreads();

    f32x4 acc[4];
    #pragma unroll
    for (int nf = 0; nf < 4; ++nf) acc[nf] = (f32x4){0.f, 0.f, 0.f, 0.f};
    #pragma unroll
    for (int kc = 0; kc < 2; ++kc) {
        const f16x8 afr = *(const f16x8*)&a_t[(wave * 16 + l15) * 72 + kc * 32 + kq * 8];
        #pragma unroll
        for (int nf = 0; nf < 4; ++nf) {
            const f16x8 bfr = *(const f16x8*)(wB0h + (size_t)(nf * 16 + l15) * 64 + kc * 32 + kq * 8);
            acc[nf] = __builtin_amdgcn_mfma_f32_16x16x32_f16(afr, bfr, acc[nf], 0, 0, 0);
        }
    }

    const int pl = wave * 16 + kq * 4;
    const size_t pixbase = (size_t)b * HW + (size_t)(y0 + pl / TW) * W + x0 + pl % TW;
    float s[4] = {0.f, 0.f, 0.f, 0.f};
    #pragma unroll
    for (int nf = 0; nf < 4; ++nf) {
        const int oc = nf * 16 + l15;
        #pragma unroll
        for (int r = 0; r < 4; ++r) {
            const size_t idx = (pixbase + r) * 64 + oc;
            const float hv = h[idx] * acc[nf][r];
            h[idx] = hv;
            s[r] += hv;
        }
    }
    #pragma unroll
    for (int mm = 1; mm < 16; mm <<= 1) {
        #pragma unroll
        for (int r = 0; r < 4; ++r) s[r] += __shfl_xor(s[r], mm);
    }
    if (l15 == 0) {
        float* sp_ = Sout + pixbase;
        sp_[0] = s[0]; sp_[1] = s[1]; sp_[2] = s[2]; sp_[3] = s[3];
    }
}

// ---------------------------------------------------------------------------
// posty (MFMA 1x1 conv), two-pass. Tile = 2 rows x 32 cols (for fused pooling).
//   MODE 0: stats pass -> per-WG (sum y, sum y^2) partials.
//   MODE 1: final pass -> pool 2x2 + BN affine -> f16 NHWC out.
//   MODE 2: final pass -> fp32 NCHW out (d_out).
// ---------------------------------------------------------------------------
template<int C, int MODE>
__global__ __launch_bounds__(256) void posty_kernel(
    const float* __restrict__ h, const float* __restrict__ S,
    const _Float16* __restrict__ w1h, const float* __restrict__ bias,
    const float* __restrict__ bnst, float* __restrict__ part,
    void* __restrict__ outp, int H, int W)
{
    constexpr int NF = C / 16, CP = C + 8;
    __shared__ _Float16 a_t[64 * CP];
    __shared__ float rs_t[64];
    __shared__ float sred1[MODE == 0 ? 4 * C : 1];
    __shared__ float sred2[MODE == 0 ? 4 * C : 1];

    const int tid = threadIdx.x;
    const int lane = tid & 63, wave = tid >> 6;
    const int kq = lane >> 4, l15 = lane & 15;
    const int WT = W / 32;
    const int tx = blockIdx.x % WT, ty = blockIdx.x / WT;
    const int b = blockIdx.y;
    const int HW = H * W;

    if (tid < 64) {
        const int gp = (2 * ty + (tid >> 5)) * W + tx * 32 + (tid & 31);
        rs_t[tid] = 1.f / (S[(size_t)b * HW + gp] + EPSV);
    }
    __syncthreads();
    for (int i = tid; i < 64 * (C / 8); i += 256) {
        const int sp = i / (C / 8), seg = i % (C / 8);
        const int gp = (2 * ty + (sp >> 5)) * W + tx * 32 + (sp & 31);
        const float* src = h + ((size_t)b * HW + gp) * C + seg * 8;
        const float4 a = *(const float4*)src;
        const float4 c = *(const float4*)(src + 4);
        const float f = rs_t[sp];
        unsigned* d = (unsigned*)&a_t[sp * CP + seg * 8];
        d[0] = pack2f16(a.x * f, a.y * f);
        d[1] = pack2f16(a.z * f, a.w * f);
        d[2] = pack2f16(c.x * f, c.y * f);
        d[3] = pack2f16(c.z * f, c.w * f);
    }
    __syncthreads();

    f32x4 acc[NF];
    #pragma unroll
    for (int nf = 0; nf < NF; ++nf) acc[nf] = (f32x4){0.f, 0.f, 0.f, 0.f};
    #pragma unroll
    for (int kc = 0; kc < C / 32; ++kc) {
        const f16x8 afr = *(const f16x8*)&a_t[(wave * 16 + l15) * CP + kc * 32 + kq * 8];
        #pragma unroll
        for (int nf = 0; nf < NF; ++nf) {
            const f16x8 bfr = *(const f16x8*)(w1h + (size_t)(nf * 16 + l15) * C + kc * 32 + kq * 8);
            acc[nf] = __builtin_amdgcn_mfma_f32_16x16x32_f16(afr, bfr, acc[nf], 0, 0, 0);
        }
    }

    const int pl = wave * 16 + kq * 4;

    if constexpr (MODE == 0) {
        const int wgid = b * gridDim.x + blockIdx.x;
        #pragma unroll
        for (int nf = 0; nf < NF; ++nf) {
            const int oc = nf * 16 + l15;
            const float bv = bias[oc];
            float s1 = 0.f, s2 = 0.f;
            #pragma unroll
            for (int r = 0; r < 4; ++r) {
                const float y = fmaxf(acc[nf][r] + bv, 0.f);
                s1 += y; s2 += y * y;
            }
            s1 += __shfl_xor(s1, 16); s2 += __shfl_xor(s2, 16);
            s1 += __shfl_xor(s1, 32); s2 += __shfl_xor(s2, 32);
            if (kq == 0) {
                sred1[wave * C + oc] = s1;
                sred2[wave * C + oc] = s2;
            }
        }
        __syncthreads();
        for (int oc = tid; oc < C; oc += 256) {
            const float s1 = sred1[oc] + sred1[C + oc] + sred1[2 * C + oc] + sred1[3 * C + oc];
            const float s2 = sred2[oc] + sred2[C + oc] + sred2[2 * C + oc] + sred2[3 * C + oc];
            part[((size_t)wgid * C + oc) * 2 + 0] = s1;
            part[((size_t)wgid * C + oc) * 2 + 1] = s2;
        }
    } else {
        __syncthreads();        // all A-reads complete; reuse a_t for Y
        #pragma unroll
        for (int nf = 0; nf < NF; ++nf) {
            const int oc = nf * 16 + l15;
            const float bv = bias[oc];
            #pragma unroll
            for (int r = 0; r < 4; ++r)
                a_t[(pl + r) * CP + oc] = (_Float16)fmaxf(acc[nf][r] + bv, 0.f);
        }
        __syncthreads();
        const int Wo = W >> 1;
        for (int i = tid; i < 16 * C; i += 256) {
            int ox, c;
            if constexpr (MODE == 1) { c = i % C; ox = i / C; }
            else                     { ox = i % 16; c = i / 16; }
            const float y00 = (float)a_t[(2 * ox) * CP + c];
            const float y01 = (float)a_t[(2 * ox + 1) * CP + c];
            const float y10 = (float)a_t[(32 + 2 * ox) * CP + c];
            const float y11 = (float)a_t[(32 + 2 * ox + 1) * CP + c];
            const float v = (y00 + y01 + y10 + y11) * 0.25f * bnst[c] + bnst[C + c];
            if constexpr (MODE == 1) {
                ((_Float16*)outp)[((size_t)b * (HW >> 2) + (size_t)ty * Wo + tx * 16 + ox) * C + c] =
                    (_Float16)v;
            } else {
                ((float*)outp)[(((size_t)b * C + c) * (size_t)(H >> 1) + ty) * Wo + tx * 16 + ox] = v;
            }
        }
    }
}

// Reduce partials -> per-channel (scale, shift) for BN affine.
template<int C>
__global__ __launch_bounds__(256) void stats_kernel(const float* __restrict__ part, int nwg, float invM,
                                                    const float* __restrict__ gamma,
                                                    const float* __restrict__ beta,
                                                    float* __restrict__ stats)
{
    const int oc = blockIdx.x;
    const int tid = threadIdx.x;
    float s1 = 0.f, s2 = 0.f;
    for (int w = tid; w < nwg; w += 256) {
        s1 += part[((size_t)w * C + oc) * 2 + 0];
        s2 += part[((size_t)w * C + oc) * 2 + 1];
    }
    __shared__ float r1[4], r2[4];
    #pragma unroll
    for (int m = 32; m; m >>= 1) { s1 += __shfl_xor(s1, m, 64); s2 += __shfl_xor(s2, m, 64); }
    if ((tid & 63) == 0) { r1[tid >> 6] = s1; r2[tid >> 6] = s2; }
    __syncthreads();
    if (tid == 0) {
        s1 = r1[0] + r1[1] + r1[2] + r1[3];
        s2 = r2[0] + r2[1] + r2[2] + r2[3];
        const float mean = s1 * invM;
        const float var  = s2 * invM - mean * mean;
        const float rstd = rsqrtf(var + BNEPS);
        const float scale = gamma[oc] * rstd;
        stats[oc]     = scale;
        stats[C + oc] = beta[oc] - mean * scale;
    }
}

// ---------------------------------------------------------------------------
extern "C" void kernel_launch(void* const* d_in, const int* in_sizes, int n_in,
                              void* d_out, int out_size, void* d_ws, size_t ws_size,
                              hipStream_t stream)
{
    const float* x = (const float*)d_in[0];
    float* ws      = (float*)d_ws;
    float* h       = ws;                    // 16,777,216 f32 (max: block0)
    float* S       = h + 16777216;          //    262,144
    float* part    = S + 262144;            //  1,048,576 (posty partials / block2 S-partials)
    float* bnstats = part + 1048576;        //        512
    _Float16* xnh    = (_Float16*)(bnstats + 512);  // 4,194,304 f16
    _Float16* ratioh = xnh + 4194304;               // 4,194,304 f16
    _Float16* out0h  = ratioh + 4194304;            // 4,194,304 f16
    _Float16* out1h  = out0h + 4194304;             // 2,097,152 f16
    _Float16* wAh    = out1h + 2097152;             //   294,912 f16
    _Float16* wBh    = wAh + 294912;                //   294,912 f16
    _Float16* w1h    = wBh + 294912;                //    65,536 f16
    _Float16* wA0h   = w1h + 65536;                 //     9,216 f16
    _Float16* wB0h   = wA0h + 9216;                 //     4,096 f16  (adjacent to wA0h)

    const int B = 16;

    // ---------------- Block 0: Cin=3, Cout=64, 128x128 ----------------
    {
        const int H = 128, W = 128, HW = H * W, npx = B * HW;
        zero_f16_kernel<<<(13312 + 255) / 256, 256, 0, stream>>>(wA0h, 13312);
        prep_w0_kernel<<<64, 64, 0, stream>>>((const float*)d_in[1], wA0h, wB0h);
        xn0_kernel<<<npx / 256, 256, 0, stream>>>(x, xnh, npx, HW);
        init_h_kernel<<<(npx * 64 + 255) / 256, 256, 0, stream>>>(h, S, npx * 64, npx, 64.f);
        for (int it = 0; it < 5; ++it) {
            mfconv_nhwc<64, 16, 4, 16, 1, 4, 4, true, false, false>
                <<<dim3(8, 32, B), 256, 0, stream>>>(h, wA0h, xnh, ratioh, S, nullptr, H, W, 0);
            mf0u_kernel<<<dim3(8, 32, B), 256, 0, stream>>>(ratioh, wB0h, h, S, H, W);
        }
        prep_w1h_kernel<<<16, 256, 0, stream>>>((const float*)d_in[2], w1h, 64 * 64);
        dim3 pg((W / 32) * (H / 2), B);
        posty_kernel<64, 0><<<pg, 256, 0, stream>>>(h, S, w1h, (const float*)d_in[3],
                                                    nullptr, part, nullptr, H, W);
        stats_kernel<64><<<64, 256, 0, stream>>>(part, pg.x * pg.y, 1.0f / (float)npx,
                                                 (const float*)d_in[4], (const float*)d_in[5], bnstats);
        posty_kernel<64, 1><<<pg, 256, 0, stream>>>(h, S, w1h, (const float*)d_in[3],
                                                    bnstats, nullptr, out0h, H, W);
    }

    // ---------------- Block 1: Cin=64, Cout=128, 64x64 ----------------
    {
        const int H = 64, W = 64, HW = H * W, npx = B * HW;
        prep_w_f16_kernel<64, 128><<<128, 256, 0, stream>>>((const float*)d_in[6], wAh, wBh);
        xn12_kernel<64><<<npx / 256, 256, 0, stream>>>(out0h, xnh, npx);
        init_h_kernel<<<(npx * 128 + 255) / 256, 256, 0, stream>>>(h, S, npx * 128, npx, 128.f);
        for (int it = 0; it < 5; ++it) {
            mfconv_nhwc<128, 64, 4, 16, 1, 64, 64, true, false, false>
                <<<dim3(4, 16, B), 256, 0, stream>>>(h, wAh, xnh, ratioh, S, nullptr, H, W, 0);
            mfconv_nhwc<64, 128, 4, 16, 1, 128, 128, false, true, true>
                <<<dim3(4, 16, B), 256, 0, stream>>>(ratioh, wBh, nullptr, h, nullptr, S, H, W, 0);
        }
        prep_w1h_kernel<<<64, 256, 0, stream>>>((const float*)d_in[7], w1h, 128 * 128);
        dim3 pg((W / 32) * (H / 2), B);
        posty_kernel<128, 0><<<pg, 256, 0, stream>>>(h, S, w1h, (const float*)d_in[8],
                                                     nullptr, part, nullptr, H, W);
        stats_kernel<128><<<128, 256, 0, stream>>>(part, pg.x * pg.y, 1.0f / (float)npx,
                                                   (const float*)d_in[9], (const float*)d_in[10], bnstats);
        posty_kernel<128, 1><<<pg, 256, 0, stream>>>(h, S, w1h, (const float*)d_in[8],
                                                     bnstats, nullptr, out1h, H, W);
    }

    // ---------------- Block 2: Cin=128, Cout=256, 32x32 ----------------
    {
        const int H = 32, W = 32, HW = H * W, npx = B * HW;
        prep_w_f16_kernel<128, 256><<<256, 256, 0, stream>>>((const float*)d_in[11], wAh, wBh);
        xn12_kernel<128><<<npx / 256, 256, 0, stream>>>(out1h, xnh, npx);
        init_h_kernel<<<(npx * 256 + 255) / 256, 256, 0, stream>>>(h, S, npx * 256, npx, 256.f);
        for (int it = 0; it < 5; ++it) {
            mfconv_nhwc<256, 128, 8, 8, 2, 128, 128, true, false, false>
                <<<dim3(8, 4, B), 256, 0, stream>>>(h, wAh, xnh, ratioh, S, nullptr, H, W, 0);
            mfconv_nhwc<128, 256, 8, 8, 2, 256, 256, false, true, true>
                <<<dim3(8, 4, B), 256, 0, stream>>>(ratioh, wBh, nullptr, h, nullptr, part, H, W, npx);
            combine_S_kernel<<<(npx + 255) / 256, 256, 0, stream>>>(part, S, npx);
        }
        prep_w1h_kernel<<<256, 256, 0, stream>>>((const float*)d_in[12], w1h, 256 * 256);
        dim3 pg((W / 32) * (H / 2), B);
        posty_kernel<256, 0><<<pg, 256, 0, stream>>>(h, S, w1h, (const float*)d_in[13],
                                                     nullptr, part, nullptr, H, W);
        stats_kernel<256><<<256, 256, 0, stream>>>(part, pg.x * pg.y, 1.0f / (float)npx,
                                                   (const float*)d_in[14], (const float*)d_in[15], bnstats);
        posty_kernel<256, 2><<<pg, 256, 0, stream>>>(h, S, w1h, (const float*)d_in[13],
                                                     bnstats, nullptr, d_out, H, W);
    }
}

// Round 7
// 1976.884 us; speedup vs baseline: 3.8782x; 1.0346x over previous
//
#include <hip/hip_runtime.h>

#define EPSV  1e-20f
#define BNEPS 1e-5f

typedef _Float16 f16x8 __attribute__((ext_vector_type(8)));
typedef _Float16 f16x4 __attribute__((ext_vector_type(4)));
typedef float    f32x4 __attribute__((ext_vector_type(4)));

__device__ inline unsigned pack2f16(float a, float b) {
    unsigned short ua = __builtin_bit_cast(unsigned short, (_Float16)a);
    unsigned short ub = __builtin_bit_cast(unsigned short, (_Float16)b);
    return ((unsigned)ub << 16) | ua;
}

// ---------------------------------------------------------------------------
// Weight prep (blocks 1/2): wn = |w|/(sum+eps), f16 GEMM layouts
//   wBh[tap][co][ci]  (update conv: n=co, k=ci)
//   wAh[tapf][ci][co] (ratio conv:  n=ci, k=co)
// ---------------------------------------------------------------------------
template<int CIN, int COUT>
__global__ __launch_bounds__(256) void prep_w_f16_kernel(const float* __restrict__ w,
                                                         _Float16* __restrict__ wAh,
                                                         _Float16* __restrict__ wBh)
{
    const int co  = blockIdx.x;
    const int tid = threadIdx.x;
    const int N   = CIN * 9;
    const float* wrow = w + (size_t)co * N;

    float s = 0.f;
    for (int i = tid; i < N; i += 256) s += fabsf(wrow[i]);
    __shared__ float red[4];
    #pragma unroll
    for (int m = 32; m; m >>= 1) s += __shfl_xor(s, m, 64);
    if ((tid & 63) == 0) red[tid >> 6] = s;
    __syncthreads();
    s = red[0] + red[1] + red[2] + red[3];
    const float rn = 1.f / (s + EPSV);

    for (int i = tid; i < N; i += 256) {
        const int ci = i / 9, tap = i % 9;
        const int ky = tap / 3, kx = tap % 3;
        const float v = fabsf(wrow[i]) * rn;
        const int tf = (2 - ky) * 3 + (2 - kx);
        wBh[((size_t)tap * COUT + co) * CIN + ci] = (_Float16)v;
        wAh[((size_t)tf * CIN + ci) * COUT + co] = (_Float16)v;
    }
}

// Block0 weight prep: wB0h[co][tap*4+ci] (K=36 pad 64), wA0h[tapf][ci(16p)][co(64)]
__global__ __launch_bounds__(256) void zero_f16_kernel(_Float16* __restrict__ a, int n)
{
    const int i = blockIdx.x * 256 + threadIdx.x;
    if (i < n) a[i] = (_Float16)0.f;
}

__global__ __launch_bounds__(64) void prep_w0_kernel(const float* __restrict__ w,
                                                     _Float16* __restrict__ wA0h,
                                                     _Float16* __restrict__ wB0h)
{
    const int co = blockIdx.x, tid = threadIdx.x;  // 64 threads, 1 wave
    float s = (tid < 27) ? fabsf(w[co * 27 + tid]) : 0.f;
    #pragma unroll
    for (int m = 32; m; m >>= 1) s += __shfl_xor(s, m, 64);
    const float rn = 1.f / (s + EPSV);
    if (tid < 27) {
        const int ci = tid / 9, tap = tid % 9, ky = tap / 3, kx = tap % 3;
        const float v = fabsf(w[co * 27 + tid]) * rn;
        wB0h[co * 64 + tap * 4 + ci] = (_Float16)v;
        wA0h[(((2 - ky) * 3 + (2 - kx)) * 16 + ci) * 64 + co] = (_Float16)v;
    }
}

__global__ __launch_bounds__(256) void prep_w1h_kernel(const float* __restrict__ w1,
                                                       _Float16* __restrict__ w1h, int n)
{
    const int i = blockIdx.x * 256 + threadIdx.x;
    if (i < n) w1h[i] = (_Float16)w1[i];
}

// ---------------------------------------------------------------------------
// xn prep.
// ---------------------------------------------------------------------------
__global__ __launch_bounds__(256) void xn0_kernel(const float* __restrict__ x,
                                                  _Float16* __restrict__ xn4,
                                                  int npx, int HW)
{
    const int p = blockIdx.x * 256 + threadIdx.x;
    if (p >= npx) return;
    const int b = p / HW, r = p % HW;
    const float* ip = x + (size_t)b * 3 * HW + r;
    const float v0 = fmaxf(ip[0], 0.f), v1 = fmaxf(ip[HW], 0.f), v2 = fmaxf(ip[2 * HW], 0.f);
    const float rs = 1.f / (v0 + v1 + v2 + EPSV);
    unsigned* d = (unsigned*)(xn4 + (size_t)p * 4);
    d[0] = pack2f16(v0 * rs, v1 * rs);
    d[1] = pack2f16(v2 * rs, 0.f);
}

template<int C>
__global__ __launch_bounds__(256) void xn12_kernel(const _Float16* __restrict__ prev,
                                                   _Float16* __restrict__ xn, int npx)
{
    const int p = blockIdx.x * 256 + threadIdx.x;
    if (p >= npx) return;
    const _Float16* ip = prev + (size_t)p * C;
    _Float16* op = xn + (size_t)p * C;
    f16x8 buf[C / 8];
    float s = 0.f;
    #pragma unroll
    for (int g = 0; g < C / 8; ++g) {
        buf[g] = *(const f16x8*)(ip + g * 8);
        #pragma unroll
        for (int j = 0; j < 8; ++j) {
            float v = fmaxf((float)buf[g][j], 0.f);
            s += v;
            buf[g][j] = (_Float16)v;
        }
    }
    const float rs = 1.f / (s + EPSV);
    #pragma unroll
    for (int g = 0; g < C / 8; ++g) {
        f16x8 o;
        #pragma unroll
        for (int j = 0; j < 8; ++j) o[j] = (_Float16)((float)buf[g][j] * rs);
        *(f16x8*)(op + g * 8) = o;
    }
}

__global__ __launch_bounds__(256) void init_h_kernel(_Float16* __restrict__ h, float* __restrict__ S,
                                                     int nh, int ns, float cval)
{
    const int i = blockIdx.x * 256 + threadIdx.x;
    if (i < nh) h[i] = (_Float16)1.f;
    if (i < ns) S[i] = cval;
}

template<int NS>
__global__ __launch_bounds__(256) void combine_S_kernel(const float* __restrict__ sp,
                                                        float* __restrict__ S, int npx)
{
    const int i = blockIdx.x * 256 + threadIdx.x;
    if (i >= npx) return;
    float s = sp[i];
    #pragma unroll
    for (int k = 1; k < NS; ++k) s += sp[(size_t)k * npx + i];
    S[i] = s;
}

// ---------------------------------------------------------------------------
// NHWC f16 MFMA implicit-GEMM 3x3 'same' conv, 2-phase pipelined staging.
//   64-pixel tile (TH x TW), 4 waves; WG owns OCWG = OCg/NSPLIT ocs.
//   Double-buffered LDS input; chunk c+1 global loads issued before compute(c).
//   NORM_IN: staged input scaled by 1/(Sin+eps) (ratio conv, in = h).
//   !UPDATE: out = aux/(acc+eps) f16, stride OST, only oc<NW written.
//   UPDATE : h f16 RMW (*= acc), S partials (NSPLIT>1: at split*sstride).
// Weights: wgt[tap][n(OCg)][k(ICg)] f16.
// ---------------------------------------------------------------------------
template<int ICg, int OCg, int TH, int TW, int NSPLIT, int OST, int NW,
         bool NORM_IN, bool UPDATE>
__global__ __launch_bounds__(256) void mfconv2(
    const _Float16* __restrict__ in, const _Float16* __restrict__ wgt,
    const _Float16* __restrict__ aux, _Float16* __restrict__ out,
    const float* __restrict__ Sin, float* __restrict__ Sout,
    int H, int W, int sstride)
{
    constexpr int OCWG = OCg / NSPLIT;
    constexpr int NF = OCWG / 16;
    constexpr int HS = TH + 2, WSp = TW + 2, NSP = HS * WSp;
    constexpr int ICB = 32, ICP = ICB + 8, NCH = ICg / ICB;
    constexpr int LS = (NSPLIT == 4) ? 2 : (NSPLIT == 2) ? 1 : 0;
    constexpr int NLD = NSP * 4;
    constexpr int IREG = (NLD + 255) / 256;
    static_assert(TH * TW == 64 && OCWG % 16 == 0 && ICg % 32 == 0, "cfg");

    __shared__ _Float16 in_t[2][NSP * ICP];
    __shared__ float rS[NORM_IN ? NSP : 1];

    const int tid = threadIdx.x;
    const int lane = tid & 63, wave = tid >> 6;
    const int kq = lane >> 4, l15 = lane & 15;
    const int split = blockIdx.x & (NSPLIT - 1);
    const int tx = blockIdx.x >> LS;
    const int x0 = tx * TW, y0 = blockIdx.y * TH, b = blockIdx.z;
    const int HW = H * W;
    const int oc0 = split * OCWG;

    if constexpr (NORM_IN) {
        for (int i = tid; i < NSP; i += 256) {
            const int yy = y0 + i / WSp - 1, xx = x0 + i % WSp - 1;
            float sv = 0.f;
            if (yy >= 0 && yy < H && xx >= 0 && xx < W)
                sv = Sin[(size_t)b * HW + (size_t)yy * W + xx];
            rS[i] = 1.f / (sv + EPSV);
        }
    }

    const int m = wave * 16 + l15;
    const int pyl = m / TW, pxl = m % TW;

    f16x8 ld[IREG];

    // --- helpers expressed as lambdas (compile-time unrolled) ---
    auto regload = [&](int icc) {
        const int ic0 = icc * ICB;
        #pragma unroll
        for (int r = 0; r < IREG; ++r) {
            const int i = tid + r * 256;
            f16x8 v = {0, 0, 0, 0, 0, 0, 0, 0};
            if (i < NLD) {
                const int sp = i >> 2, seg = i & 3;
                const int yy = y0 + sp / WSp - 1, xx = x0 + sp % WSp - 1;
                if (yy >= 0 && yy < H && xx >= 0 && xx < W)
                    v = *(const f16x8*)(in +
                        ((size_t)b * HW + (size_t)yy * W + xx) * ICg + ic0 + seg * 8);
            }
            ld[r] = v;
        }
    };
    auto ldswrite = [&](int buf) {
        #pragma unroll
        for (int r = 0; r < IREG; ++r) {
            const int i = tid + r * 256;
            if (i < NLD) {
                const int sp = i >> 2, seg = i & 3;
                if constexpr (NORM_IN) {
                    const float f = rS[sp];
                    unsigned* d = (unsigned*)&in_t[buf][sp * ICP + seg * 8];
                    d[0] = pack2f16((float)ld[r][0] * f, (float)ld[r][1] * f);
                    d[1] = pack2f16((float)ld[r][2] * f, (float)ld[r][3] * f);
                    d[2] = pack2f16((float)ld[r][4] * f, (float)ld[r][5] * f);
                    d[3] = pack2f16((float)ld[r][6] * f, (float)ld[r][7] * f);
                } else {
                    *(f16x8*)&in_t[buf][sp * ICP + seg * 8] = ld[r];
                }
            }
        }
    };

    f32x4 acc[NF];
    #pragma unroll
    for (int nf = 0; nf < NF; ++nf) acc[nf] = (f32x4){0.f, 0.f, 0.f, 0.f};

    // prologue
    regload(0);
    if constexpr (NORM_IN) __syncthreads();   // rS ready before use in ldswrite
    ldswrite(0);
    __syncthreads();

    int cur = 0;
    for (int icc = 0; icc < NCH; ++icc) {
        if (icc + 1 < NCH) regload(icc + 1);   // issue-early (T14)
        const int ic0 = icc * ICB;
        #pragma unroll
        for (int tap = 0; tap < 9; ++tap) {
            const int dy = tap / 3, dx = tap % 3;
            f16x8 bfr[NF];
            #pragma unroll
            for (int nf = 0; nf < NF; ++nf) {
                const int oc = oc0 + nf * 16 + l15;
                bfr[nf] = *(const f16x8*)(
                    wgt + ((size_t)tap * OCg + oc) * ICg + ic0 + kq * 8);
            }
            const int sp = (pyl + dy) * WSp + pxl + dx;
            const f16x8 afr = *(const f16x8*)&in_t[cur][sp * ICP + kq * 8];
            #pragma unroll
            for (int nf = 0; nf < NF; ++nf)
                acc[nf] = __builtin_amdgcn_mfma_f32_16x16x32_f16(afr, bfr[nf], acc[nf], 0, 0, 0);
        }
        if (icc + 1 < NCH) {
            ldswrite(cur ^ 1);     // other buffer: safe while peers still compute cur
            __syncthreads();
            cur ^= 1;
        }
    }

    // epilogue
    const int pl = wave * 16 + kq * 4;
    const int py0 = pl / TW, px0 = pl % TW;
    const size_t pixbase = (size_t)b * HW + (size_t)(y0 + py0) * W + x0 + px0;

    if constexpr (!UPDATE) {
        #pragma unroll
        for (int nf = 0; nf < NF; ++nf) {
            const int oc = oc0 + nf * 16 + l15;
            if (oc < NW) {
                #pragma unroll
                for (int r = 0; r < 4; ++r) {
                    const size_t idx = (pixbase + r) * OST + oc;
                    out[idx] = (_Float16)((float)aux[idx] / (acc[nf][r] + EPSV));
                }
            }
        }
    } else {
        float s[4] = {0.f, 0.f, 0.f, 0.f};
        #pragma unroll
        for (int nf = 0; nf < NF; ++nf) {
            const int oc = oc0 + nf * 16 + l15;
            #pragma unroll
            for (int r = 0; r < 4; ++r) {
                const size_t idx = (pixbase + r) * OST + oc;
                const float hv = (float)out[idx] * acc[nf][r];
                const _Float16 hq = (_Float16)hv;
                out[idx] = hq;
                s[r] += (float)hq;
            }
        }
        #pragma unroll
        for (int mm = 1; mm < 16; mm <<= 1) {
            #pragma unroll
            for (int r = 0; r < 4; ++r) s[r] += __shfl_xor(s[r], mm);
        }
        if (l15 == 0) {
            float* sp_ = Sout + (size_t)split * sstride + pixbase;
            sp_[0] = s[0]; sp_[1] = s[1]; sp_[2] = s[2]; sp_[3] = s[3];
        }
    }
}

// ---------------------------------------------------------------------------
// Block0 update conv (3 -> 64) via im2col MFMA, h f16 RMW.
// ---------------------------------------------------------------------------
__global__ __launch_bounds__(256) void mf0u_kernel(
    const _Float16* __restrict__ ratio4, const _Float16* __restrict__ wB0h,
    _Float16* __restrict__ h, float* __restrict__ Sout, int H, int W)
{
    constexpr int TW = 16;
    __shared__ _Float16 a_t[64 * 72];

    const int tid = threadIdx.x;
    const int lane = tid & 63, wave = tid >> 6;
    const int kq = lane >> 4, l15 = lane & 15;
    const int x0 = blockIdx.x * TW, y0 = blockIdx.y * 4, b = blockIdx.z;
    const int HW = H * W;

    for (int i = tid; i < 64 * 72 / 2; i += 256) ((unsigned*)a_t)[i] = 0;
    __syncthreads();
    for (int i = tid; i < 576; i += 256) {
        const int px = i / 9, tap = i % 9;
        const int py = px / TW, pxx = px % TW;
        const int yy = y0 + py + tap / 3 - 1, xx = x0 + pxx + tap % 3 - 1;
        if (yy >= 0 && yy < H && xx >= 0 && xx < W)
            *(f16x4*)&a_t[px * 72 + tap * 4] =
                *(const f16x4*)(ratio4 + ((size_t)b * HW + (size_t)yy * W + xx) * 4);
    }
    __syncthreads();

    f32x4 acc[4];
    #pragma unroll
    for (int nf = 0; nf < 4; ++nf) acc[nf] = (f32x4){0.f, 0.f, 0.f, 0.f};
    #pragma unroll
    for (int kc = 0; kc < 2; ++kc) {
        const f16x8 afr = *(const f16x8*)&a_t[(wave * 16 + l15) * 72 + kc * 32 + kq * 8];
        #pragma unroll
        for (int nf = 0; nf < 4; ++nf) {
            const f16x8 bfr = *(const f16x8*)(wB0h + (size_t)(nf * 16 + l15) * 64 + kc * 32 + kq * 8);
            acc[nf] = __builtin_amdgcn_mfma_f32_16x16x32_f16(afr, bfr, acc[nf], 0, 0, 0);
        }
    }

    const int pl = wave * 16 + kq * 4;
    const size_t pixbase = (size_t)b * HW + (size_t)(y0 + pl / TW) * W + x0 + pl % TW;
    float s[4] = {0.f, 0.f, 0.f, 0.f};
    #pragma unroll
    for (int nf = 0; nf < 4; ++nf) {
        const int oc = nf * 16 + l15;
        #pragma unroll
        for (int r = 0; r < 4; ++r) {
            const size_t idx = (pixbase + r) * 64 + oc;
            const float hv = (float)h[idx] * acc[nf][r];
            const _Float16 hq = (_Float16)hv;
            h[idx] = hq;
            s[r] += (float)hq;
        }
    }
    #pragma unroll
    for (int mm = 1; mm < 16; mm <<= 1) {
        #pragma unroll
        for (int r = 0; r < 4; ++r) s[r] += __shfl_xor(s[r], mm);
    }
    if (l15 == 0) {
        float* sp_ = Sout + pixbase;
        sp_[0] = s[0]; sp_[1] = s[1]; sp_[2] = s[2]; sp_[3] = s[3];
    }
}

// ---------------------------------------------------------------------------
// posty (MFMA 1x1 conv), two-pass; h f16. Tile = 2 rows x 32 cols.
//   MODE 0: stats partials. MODE 1: pool+BN -> f16 NHWC. MODE 2: fp32 NCHW.
// ---------------------------------------------------------------------------
template<int C, int MODE>
__global__ __launch_bounds__(256) void posty_kernel(
    const _Float16* __restrict__ h, const float* __restrict__ S,
    const _Float16* __restrict__ w1h, const float* __restrict__ bias,
    const float* __restrict__ bnst, float* __restrict__ part,
    void* __restrict__ outp, int H, int W)
{
    constexpr int NF = C / 16, CP = C + 8;
    __shared__ _Float16 a_t[64 * CP];
    __shared__ float rs_t[64];
    __shared__ float sred1[MODE == 0 ? 4 * C : 1];
    __shared__ float sred2[MODE == 0 ? 4 * C : 1];

    const int tid = threadIdx.x;
    const int lane = tid & 63, wave = tid >> 6;
    const int kq = lane >> 4, l15 = lane & 15;
    const int WT = W / 32;
    const int tx = blockIdx.x % WT, ty = blockIdx.x / WT;
    const int b = blockIdx.y;
    const int HW = H * W;

    if (tid < 64) {
        const int gp = (2 * ty + (tid >> 5)) * W + tx * 32 + (tid & 31);
        rs_t[tid] = 1.f / (S[(size_t)b * HW + gp] + EPSV);
    }
    __syncthreads();
    for (int i = tid; i < 64 * (C / 8); i += 256) {
        const int sp = i / (C / 8), seg = i % (C / 8);
        const int gp = (2 * ty + (sp >> 5)) * W + tx * 32 + (sp & 31);
        const f16x8 v = *(const f16x8*)(h + ((size_t)b * HW + gp) * C + seg * 8);
        const float f = rs_t[sp];
        unsigned* d = (unsigned*)&a_t[sp * CP + seg * 8];
        d[0] = pack2f16((float)v[0] * f, (float)v[1] * f);
        d[1] = pack2f16((float)v[2] * f, (float)v[3] * f);
        d[2] = pack2f16((float)v[4] * f, (float)v[5] * f);
        d[3] = pack2f16((float)v[6] * f, (float)v[7] * f);
    }
    __syncthreads();

    f32x4 acc[NF];
    #pragma unroll
    for (int nf = 0; nf < NF; ++nf) acc[nf] = (f32x4){0.f, 0.f, 0.f, 0.f};
    #pragma unroll
    for (int kc = 0; kc < C / 32; ++kc) {
        const f16x8 afr = *(const f16x8*)&a_t[(wave * 16 + l15) * CP + kc * 32 + kq * 8];
        #pragma unroll
        for (int nf = 0; nf < NF; ++nf) {
            const f16x8 bfr = *(const f16x8*)(w1h + (size_t)(nf * 16 + l15) * C + kc * 32 + kq * 8);
            acc[nf] = __builtin_amdgcn_mfma_f32_16x16x32_f16(afr, bfr, acc[nf], 0, 0, 0);
        }
    }

    const int pl = wave * 16 + kq * 4;

    if constexpr (MODE == 0) {
        const int wgid = b * gridDim.x + blockIdx.x;
        #pragma unroll
        for (int nf = 0; nf < NF; ++nf) {
            const int oc = nf * 16 + l15;
            const float bv = bias[oc];
            float s1 = 0.f, s2 = 0.f;
            #pragma unroll
            for (int r = 0; r < 4; ++r) {
                const float y = fmaxf(acc[nf][r] + bv, 0.f);
                s1 += y; s2 += y * y;
            }
            s1 += __shfl_xor(s1, 16); s2 += __shfl_xor(s2, 16);
            s1 += __shfl_xor(s1, 32); s2 += __shfl_xor(s2, 32);
            if (kq == 0) {
                sred1[wave * C + oc] = s1;
                sred2[wave * C + oc] = s2;
            }
        }
        __syncthreads();
        for (int oc = tid; oc < C; oc += 256) {
            const float s1 = sred1[oc] + sred1[C + oc] + sred1[2 * C + oc] + sred1[3 * C + oc];
            const float s2 = sred2[oc] + sred2[C + oc] + sred2[2 * C + oc] + sred2[3 * C + oc];
            part[((size_t)wgid * C + oc) * 2 + 0] = s1;
            part[((size_t)wgid * C + oc) * 2 + 1] = s2;
        }
    } else {
        __syncthreads();        // all A-reads complete; reuse a_t for Y
        #pragma unroll
        for (int nf = 0; nf < NF; ++nf) {
            const int oc = nf * 16 + l15;
            const float bv = bias[oc];
            #pragma unroll
            for (int r = 0; r < 4; ++r)
                a_t[(pl + r) * CP + oc] = (_Float16)fmaxf(acc[nf][r] + bv, 0.f);
        }
        __syncthreads();
        const int Wo = W >> 1;
        for (int i = tid; i < 16 * C; i += 256) {
            int ox, c;
            if constexpr (MODE == 1) { c = i % C; ox = i / C; }
            else                     { ox = i % 16; c = i / 16; }
            const float y00 = (float)a_t[(2 * ox) * CP + c];
            const float y01 = (float)a_t[(2 * ox + 1) * CP + c];
            const float y10 = (float)a_t[(32 + 2 * ox) * CP + c];
            const float y11 = (float)a_t[(32 + 2 * ox + 1) * CP + c];
            const float v = (y00 + y01 + y10 + y11) * 0.25f * bnst[c] + bnst[C + c];
            if constexpr (MODE == 1) {
                ((_Float16*)outp)[((size_t)b * (HW >> 2) + (size_t)ty * Wo + tx * 16 + ox) * C + c] =
                    (_Float16)v;
            } else {
                ((float*)outp)[(((size_t)b * C + c) * (size_t)(H >> 1) + ty) * Wo + tx * 16 + ox] = v;
            }
        }
    }
}

// Reduce partials -> per-channel (scale, shift) for BN affine.
template<int C>
__global__ __launch_bounds__(256) void stats_kernel(const float* __restrict__ part, int nwg, float invM,
                                                    const float* __restrict__ gamma,
                                                    const float* __restrict__ beta,
                                                    float* __restrict__ stats)
{
    const int oc = blockIdx.x;
    const int tid = threadIdx.x;
    float s1 = 0.f, s2 = 0.f;
    for (int w = tid; w < nwg; w += 256) {
        s1 += part[((size_t)w * C + oc) * 2 + 0];
        s2 += part[((size_t)w * C + oc) * 2 + 1];
    }
    __shared__ float r1[4], r2[4];
    #pragma unroll
    for (int m = 32; m; m >>= 1) { s1 += __shfl_xor(s1, m, 64); s2 += __shfl_xor(s2, m, 64); }
    if ((tid & 63) == 0) { r1[tid >> 6] = s1; r2[tid >> 6] = s2; }
    __syncthreads();
    if (tid == 0) {
        s1 = r1[0] + r1[1] + r1[2] + r1[3];
        s2 = r2[0] + r2[1] + r2[2] + r2[3];
        const float mean = s1 * invM;
        const float var  = s2 * invM - mean * mean;
        const float rstd = rsqrtf(var + BNEPS);
        const float scale = gamma[oc] * rstd;
        stats[oc]     = scale;
        stats[C + oc] = beta[oc] - mean * scale;
    }
}

// ---------------------------------------------------------------------------
extern "C" void kernel_launch(void* const* d_in, const int* in_sizes, int n_in,
                              void* d_out, int out_size, void* d_ws, size_t ws_size,
                              hipStream_t stream)
{
    const float* x = (const float*)d_in[0];
    float* ws      = (float*)d_ws;
    float* S       = ws;                    //    262,144 f32
    float* part    = S + 262144;            //  1,048,576 f32
    float* bnstats = part + 1048576;        //        512 f32
    _Float16* h      = (_Float16*)(bnstats + 512); // 16,777,216 f16
    _Float16* xnh    = h + 16777216;               //  4,194,304 f16
    _Float16* ratioh = xnh + 4194304;              //  4,194,304 f16
    _Float16* out0h  = ratioh + 4194304;           //  4,194,304 f16
    _Float16* out1h  = out0h + 4194304;            //  2,097,152 f16
    _Float16* wAh    = out1h + 2097152;            //    294,912 f16
    _Float16* wBh    = wAh + 294912;               //    294,912 f16
    _Float16* w1h    = wBh + 294912;               //     65,536 f16
    _Float16* wA0h   = w1h + 65536;                //      9,216 f16
    _Float16* wB0h   = wA0h + 9216;                //      4,096 f16 (adjacent)

    const int B = 16;

    // ---------------- Block 0: Cin=3, Cout=64, 128x128 ----------------
    {
        const int H = 128, W = 128, HW = H * W, npx = B * HW;
        zero_f16_kernel<<<(13312 + 255) / 256, 256, 0, stream>>>(wA0h, 13312);
        prep_w0_kernel<<<64, 64, 0, stream>>>((const float*)d_in[1], wA0h, wB0h);
        xn0_kernel<<<npx / 256, 256, 0, stream>>>(x, xnh, npx, HW);
        init_h_kernel<<<(npx * 64 + 255) / 256, 256, 0, stream>>>(h, S, npx * 64, npx, 64.f);
        for (int it = 0; it < 5; ++it) {
            mfconv2<64, 16, 4, 16, 1, 4, 4, true, false>
                <<<dim3(8, 32, B), 256, 0, stream>>>(h, wA0h, xnh, ratioh, S, nullptr, H, W, 0);
            mf0u_kernel<<<dim3(8, 32, B), 256, 0, stream>>>(ratioh, wB0h, h, S, H, W);
        }
        prep_w1h_kernel<<<16, 256, 0, stream>>>((const float*)d_in[2], w1h, 64 * 64);
        dim3 pg((W / 32) * (H / 2), B);
        posty_kernel<64, 0><<<pg, 256, 0, stream>>>(h, S, w1h, (const float*)d_in[3],
                                                    nullptr, part, nullptr, H, W);
        stats_kernel<64><<<64, 256, 0, stream>>>(part, pg.x * pg.y, 1.0f / (float)npx,
                                                 (const float*)d_in[4], (const float*)d_in[5], bnstats);
        posty_kernel<64, 1><<<pg, 256, 0, stream>>>(h, S, w1h, (const float*)d_in[3],
                                                    bnstats, nullptr, out0h, H, W);
    }

    // ---------------- Block 1: Cin=64, Cout=128, 64x64 ----------------
    {
        const int H = 64, W = 64, HW = H * W, npx = B * HW;
        prep_w_f16_kernel<64, 128><<<128, 256, 0, stream>>>((const float*)d_in[6], wAh, wBh);
        xn12_kernel<64><<<npx / 256, 256, 0, stream>>>(out0h, xnh, npx);
        init_h_kernel<<<(npx * 128 + 255) / 256, 256, 0, stream>>>(h, S, npx * 128, npx, 128.f);
        for (int it = 0; it < 5; ++it) {
            mfconv2<128, 64, 4, 16, 2, 64, 64, true, false>
                <<<dim3(8, 16, B), 256, 0, stream>>>(h, wAh, xnh, ratioh, S, nullptr, H, W, 0);
            mfconv2<64, 128, 4, 16, 2, 128, 128, false, true>
                <<<dim3(8, 16, B), 256, 0, stream>>>(ratioh, wBh, nullptr, h, nullptr, part, H, W, npx);
            combine_S_kernel<2><<<(npx + 255) / 256, 256, 0, stream>>>(part, S, npx);
        }
        prep_w1h_kernel<<<64, 256, 0, stream>>>((const float*)d_in[7], w1h, 128 * 128);
        dim3 pg((W / 32) * (H / 2), B);
        posty_kernel<128, 0><<<pg, 256, 0, stream>>>(h, S, w1h, (const float*)d_in[8],
                                                     nullptr, part, nullptr, H, W);
        stats_kernel<128><<<128, 256, 0, stream>>>(part, pg.x * pg.y, 1.0f / (float)npx,
                                                   (const float*)d_in[9], (const float*)d_in[10], bnstats);
        posty_kernel<128, 1><<<pg, 256, 0, stream>>>(h, S, w1h, (const float*)d_in[8],
                                                     bnstats, nullptr, out1h, H, W);
    }

    // ---------------- Block 2: Cin=128, Cout=256, 32x32 ----------------
    {
        const int H = 32, W = 32, HW = H * W, npx = B * HW;
        prep_w_f16_kernel<128, 256><<<256, 256, 0, stream>>>((const float*)d_in[11], wAh, wBh);
        xn12_kernel<128><<<npx / 256, 256, 0, stream>>>(out1h, xnh, npx);
        init_h_kernel<<<(npx * 256 + 255) / 256, 256, 0, stream>>>(h, S, npx * 256, npx, 256.f);
        for (int it = 0; it < 5; ++it) {
            mfconv2<256, 128, 8, 8, 4, 128, 128, true, false>
                <<<dim3(16, 4, B), 256, 0, stream>>>(h, wAh, xnh, ratioh, S, nullptr, H, W, 0);
            mfconv2<128, 256, 8, 8, 4, 256, 256, false, true>
                <<<dim3(16, 4, B), 256, 0, stream>>>(ratioh, wBh, nullptr, h, nullptr, part, H, W, npx);
            combine_S_kernel<4><<<(npx + 255) / 256, 256, 0, stream>>>(part, S, npx);
        }
        prep_w1h_kernel<<<256, 256, 0, stream>>>((const float*)d_in[12], w1h, 256 * 256);
        dim3 pg((W / 32) * (H / 2), B);
        posty_kernel<256, 0><<<pg, 256, 0, stream>>>(h, S, w1h, (const float*)d_in[13],
                                                     nullptr, part, nullptr, H, W);
        stats_kernel<256><<<256, 256, 0, stream>>>(part, pg.x * pg.y, 1.0f / (float)npx,
                                                   (const float*)d_in[14], (const float*)d_in[15], bnstats);
        posty_kernel<256, 2><<<pg, 256, 0, stream>>>(h, S, w1h, (const float*)d_in[13],
                                                     bnstats, nullptr, d_out, H, W);
    }
}